// Round 1
// baseline (704.459 us; speedup 1.0000x reference)
//
#include <hip/hip_runtime.h>
#include <hip/hip_bf16.h>
#include <math.h>

#define DIM 1024
#define NHEADS 16
#define HD 64
#define TT 2048
#define BB 4
#define MTOK (BB*TT)
#define HID 4096

typedef __attribute__((ext_vector_type(8))) short bf16x8;
typedef __attribute__((ext_vector_type(4))) float f32x4;
typedef unsigned short u16;

__device__ inline u16 f2b(float f){
  __hip_bfloat16 h = __float2bfloat16(f);
  return __builtin_bit_cast(u16, h);
}

__device__ inline void load_lds16(const void* g, void* l){
  __builtin_amdgcn_global_load_lds(
      (const __attribute__((address_space(1))) void*)g,
      (__attribute__((address_space(3))) void*)l,
      16, 0, 0);
}

// ---------------- weight transpose + f32->bf16 convert: Wt[n][k] = W[k][n]
__global__ __launch_bounds__(256) void wconv_t(const float* __restrict__ W,
                                               u16* __restrict__ Wt, int K, int N){
  __shared__ float tl[32][33];
  const int k0 = blockIdx.x*32, n0 = blockIdx.y*32;
  const int tx = threadIdx.x & 31, ty = threadIdx.x >> 5; // 32 x 8
  #pragma unroll
  for (int r=0;r<32;r+=8)
    tl[ty+r][tx] = W[(size_t)(k0+ty+r)*N + (n0+tx)];
  __syncthreads();
  #pragma unroll
  for (int r=0;r<32;r+=8)
    Wt[(size_t)(n0+ty+r)*K + (k0+tx)] = f2b(tl[tx][ty+r]);
}

// ---------------- layernorm: f32 in -> bf16 out
__global__ __launch_bounds__(256) void ln_fwd(const float* __restrict__ x,
                                              const float* __restrict__ g,
                                              const float* __restrict__ bta,
                                              u16* __restrict__ out){
  const int row = blockIdx.x, t = threadIdx.x;
  const float4 v = ((const float4*)(x + (size_t)row*DIM))[t];
  float s  = v.x+v.y+v.z+v.w;
  float s2 = v.x*v.x+v.y*v.y+v.z*v.z+v.w*v.w;
  #pragma unroll
  for (int m=1;m<64;m<<=1){ s += __shfl_xor(s,m); s2 += __shfl_xor(s2,m); }
  __shared__ float red[8];
  if ((t&63)==0){ red[t>>6]=s; red[4+(t>>6)]=s2; }
  __syncthreads();
  s  = red[0]+red[1]+red[2]+red[3];
  s2 = red[4]+red[5]+red[6]+red[7];
  const float mu = s*(1.0f/DIM);
  const float rstd = rsqrtf(s2*(1.0f/DIM) - mu*mu + 1e-5f);
  const float4 gv = ((const float4*)g)[t];
  const float4 bv = ((const float4*)bta)[t];
  ushort4 ov;
  ov.x = f2b((v.x-mu)*rstd*gv.x + bv.x);
  ov.y = f2b((v.y-mu)*rstd*gv.y + bv.y);
  ov.z = f2b((v.z-mu)*rstd*gv.z + bv.z);
  ov.w = f2b((v.w-mu)*rstd*gv.w + bv.w);
  ((ushort4*)out)[(size_t)row*(DIM/4) + t] = ov;
}

// ---------------- GEMM: C[M][N] = A[M][K](bf16) @ Bt[N][K](bf16)^T + bias, fused epilogues
// EPI 0: qkv split -> q/k/v [B,H,T,hd] bf16
// EPI 1: + resid(f32) -> outf (x2)
// EPI 2: exact gelu -> outh (act, row stride HID)
// EPI 3: + resid(f32) -> outf (final out)
template<int EPI>
__global__ __launch_bounds__(256) void gemm_bt(
    const u16* __restrict__ A, const u16* __restrict__ Bt,
    const float* __restrict__ bias, const float* __restrict__ resid,
    float* __restrict__ outf, u16* __restrict__ outh,
    u16* __restrict__ qo, u16* __restrict__ ko, u16* __restrict__ vo,
    int M, int N, int K)
{
  __shared__ __align__(16) u16 As[128*32];
  __shared__ __align__(16) u16 Bs[128*32];
  const int t = threadIdx.x, wv = t>>6, ln = t&63;
  const int m0 = blockIdx.y*128, n0 = blockIdx.x*128;
  const int wr = wv>>1, wc = wv&1;
  const int lr = (ln>>4)*4, lc = ln&15, kb8 = (ln>>4)*8;
  f32x4 acc[4][4] = {};
  for (int kt=0; kt<K; kt+=32){
    #pragma unroll
    for (int j=0;j<2;j++){
      const int chunk = wv*2+j;
      const int byteoff = (chunk<<10) + (ln<<4);
      const int row = byteoff>>6;
      const int colb = byteoff&63;
      load_lds16((const char*)(A  + (size_t)(m0+row)*K + kt) + colb, (char*)As + (chunk<<10));
      load_lds16((const char*)(Bt + (size_t)(n0+row)*K + kt) + colb, (char*)Bs + (chunk<<10));
    }
    asm volatile("s_waitcnt vmcnt(0)" ::: "memory");
    __syncthreads();
    bf16x8 af[4], bfr[4];
    #pragma unroll
    for (int mi=0;mi<4;mi++)
      af[mi] = *(const bf16x8*)&As[(wr*64 + mi*16 + lc)*32 + kb8];
    #pragma unroll
    for (int ni=0;ni<4;ni++)
      bfr[ni] = *(const bf16x8*)&Bs[(wc*64 + ni*16 + lc)*32 + kb8];
    #pragma unroll
    for (int mi=0;mi<4;mi++)
      #pragma unroll
      for (int ni=0;ni<4;ni++)
        acc[mi][ni] = __builtin_amdgcn_mfma_f32_16x16x32_bf16(af[mi], bfr[ni], acc[mi][ni], 0,0,0);
    __syncthreads();
  }
  #pragma unroll
  for (int ni=0;ni<4;ni++){
    const int gn = n0 + wc*64 + ni*16 + lc;
    const float bv = bias[gn];
    #pragma unroll
    for (int mi=0;mi<4;mi++){
      const int gmb = m0 + wr*64 + mi*16 + lr;
      f32x4 a = acc[mi][ni];
      #pragma unroll
      for (int i=0;i<4;i++){
        const int gm = gmb + i;
        float val = a[i] + bv;
        if constexpr (EPI==0){
          const int part = gn>>10, c = gn&1023;
          const int bb = gm>>11, tok = gm&2047;
          u16* dst = (part==0) ? qo : ((part==1) ? ko : vo);
          dst[(((size_t)bb*NHEADS + (c>>6))*TT + tok)*HD + (c&63)] = f2b(val);
        } else if constexpr (EPI==1){
          const size_t idx = (size_t)gm*DIM + gn;
          outf[idx] = val + resid[idx];
        } else if constexpr (EPI==2){
          const float gl = 0.5f*val*(1.0f + erff(val*0.70710678118654752f));
          outh[(size_t)gm*HID + gn] = f2b(gl);
        } else {
          const size_t idx = (size_t)gm*DIM + gn;
          outf[idx] = val + resid[idx];
        }
      }
    }
  }
}

// ---------------- causal flash attention, one block per (qblock of 64, b*h)
__global__ __launch_bounds__(256) void attn_fwd(
    const u16* __restrict__ qb, const u16* __restrict__ kb, const u16* __restrict__ vb,
    u16* __restrict__ o)
{
  __shared__ __align__(16) u16 Ks[64*72];
  __shared__ __align__(16) u16 Vs[64*72];   // transposed: Vs[d][kv]
  __shared__ __align__(16) u16 Ps[4][16*72];
  const int t = threadIdx.x, wv = t>>6, ln = t&63;
  const int qblk = gridDim.x - 1 - blockIdx.x;  // heavy blocks first
  const int bh = blockIdx.y;
  const size_t base = (size_t)bh*TT*HD;
  const int lr = (ln>>4)*4, lc = ln&15, kb8 = (ln>>4)*8;
  const int qrow = qblk*64 + wv*16 + lc;
  const bf16x8 qf0 = *(const bf16x8*)(qb + base + (size_t)qrow*HD + kb8);
  const bf16x8 qf1 = *(const bf16x8*)(qb + base + (size_t)qrow*HD + 32 + kb8);
  f32x4 oacc[4] = {};
  float mrun[4] = {-1e30f,-1e30f,-1e30f,-1e30f};
  float lrun[4] = {0.f,0.f,0.f,0.f};
  const int qg0 = qblk*64 + wv*16 + lr;
  for (int kt=0; kt<=qblk; kt++){
    __syncthreads();
    #pragma unroll
    for (int j=0;j<2;j++){
      const int c = t + j*256;
      const int row = c>>3, ce = (c&7)*8;
      *(bf16x8*)&Ks[row*72 + ce] = *(const bf16x8*)(kb + base + (size_t)(kt*64+row)*HD + ce);
      const bf16x8 vvv = *(const bf16x8*)(vb + base + (size_t)(kt*64+row)*HD + ce);
      #pragma unroll
      for (int e=0;e<8;e++) Vs[(ce+e)*72 + row] = (u16)vvv[e];
    }
    __syncthreads();
    f32x4 sf[4];
    #pragma unroll
    for (int cf=0;cf<4;cf++){
      const bf16x8 kf0 = *(const bf16x8*)&Ks[(cf*16+lc)*72 + kb8];
      const bf16x8 kf1 = *(const bf16x8*)&Ks[(cf*16+lc)*72 + 32 + kb8];
      f32x4 z = {0.f,0.f,0.f,0.f};
      z = __builtin_amdgcn_mfma_f32_16x16x32_bf16(qf0, kf0, z, 0,0,0);
      z = __builtin_amdgcn_mfma_f32_16x16x32_bf16(qf1, kf1, z, 0,0,0);
      sf[cf] = z;
    }
    float p[4][4];
    #pragma unroll
    for (int i=0;i<4;i++){
      const int qg = qg0 + i;
      float mx = -1e30f;
      #pragma unroll
      for (int cf=0;cf<4;cf++){
        const int kvg = kt*64 + cf*16 + lc;
        float sv = sf[cf][i]*0.125f;
        sv = (kvg > qg) ? -1e30f : sv;
        p[cf][i] = sv;
        mx = fmaxf(mx, sv);
      }
      #pragma unroll
      for (int msk=1;msk<16;msk<<=1) mx = fmaxf(mx, __shfl_xor(mx, msk));
      const float mnew = fmaxf(mrun[i], mx);
      const float sc = __expf(mrun[i] - mnew);
      float ssum = 0.f;
      #pragma unroll
      for (int cf=0;cf<4;cf++){
        const float pv = __expf(p[cf][i] - mnew);
        p[cf][i] = pv;
        ssum += pv;
      }
      #pragma unroll
      for (int msk=1;msk<16;msk<<=1) ssum += __shfl_xor(ssum, msk);
      lrun[i] = lrun[i]*sc + ssum;
      mrun[i] = mnew;
      #pragma unroll
      for (int df=0;df<4;df++) oacc[df][i] *= sc;
    }
    u16* pw = Ps[wv];
    #pragma unroll
    for (int cf=0;cf<4;cf++)
      #pragma unroll
      for (int i=0;i<4;i++)
        pw[(lr+i)*72 + cf*16 + lc] = f2b(p[cf][i]);
    const bf16x8 pa0 = *(const bf16x8*)&pw[lc*72 + kb8];
    const bf16x8 pa1 = *(const bf16x8*)&pw[lc*72 + 32 + kb8];
    #pragma unroll
    for (int df=0;df<4;df++){
      const bf16x8 v0 = *(const bf16x8*)&Vs[(df*16+lc)*72 + kb8];
      const bf16x8 v1 = *(const bf16x8*)&Vs[(df*16+lc)*72 + 32 + kb8];
      oacc[df] = __builtin_amdgcn_mfma_f32_16x16x32_bf16(pa0, v0, oacc[df], 0,0,0);
      oacc[df] = __builtin_amdgcn_mfma_f32_16x16x32_bf16(pa1, v1, oacc[df], 0,0,0);
    }
  }
  const int b = bh>>4, h = bh&15;
  #pragma unroll
  for (int i=0;i<4;i++){
    const float inv = 1.0f / lrun[i];
    const size_t rowb = ((size_t)b*TT + (size_t)(qg0 + i))*DIM + h*HD;
    #pragma unroll
    for (int df=0;df<4;df++)
      o[rowb + df*16 + lc] = f2b(oacc[df][i]*inv);
  }
}

extern "C" void kernel_launch(void* const* d_in, const int* in_sizes, int n_in,
                              void* d_out, int out_size, void* d_ws, size_t ws_size,
                              hipStream_t stream){
  (void)in_sizes; (void)n_in; (void)out_size; (void)ws_size;
  const float* x     = (const float*)d_in[0];
  const float* ln1g  = (const float*)d_in[1];
  const float* ln1b  = (const float*)d_in[2];
  const float* qkvw  = (const float*)d_in[3];
  const float* qkvb  = (const float*)d_in[4];
  const float* projw = (const float*)d_in[5];
  const float* projb = (const float*)d_in[6];
  const float* ln2g  = (const float*)d_in[7];
  const float* ln2b  = (const float*)d_in[8];
  const float* ff1w  = (const float*)d_in[9];
  const float* ff1b  = (const float*)d_in[10];
  const float* ff2w  = (const float*)d_in[11];
  const float* ff2b  = (const float*)d_in[12];
  float* out = (float*)d_out;

  char* ws = (char*)d_ws;
  size_t off = 0;
  auto alloc = [&](size_t n){ char* p = ws + off; off += (n + 255) & ~(size_t)255; return p; };
  u16* wqkvt  = (u16*)alloc((size_t)3072*1024*2);
  u16* wprojt = (u16*)alloc((size_t)1024*1024*2);
  u16* wff1t  = (u16*)alloc((size_t)4096*1024*2);
  u16* wff2t  = (u16*)alloc((size_t)1024*4096*2);
  u16* h1     = (u16*)alloc((size_t)MTOK*DIM*2);
  u16* qbuf   = (u16*)alloc((size_t)MTOK*DIM*2);
  u16* kbuf   = (u16*)alloc((size_t)MTOK*DIM*2);
  u16* vbuf   = (u16*)alloc((size_t)MTOK*DIM*2);
  u16* aout   = (u16*)alloc((size_t)MTOK*DIM*2);
  float* x2   = (float*)alloc((size_t)MTOK*DIM*4);
  u16* h2     = (u16*)alloc((size_t)MTOK*DIM*2);
  u16* act    = (u16*)alloc((size_t)MTOK*HID*2);

  wconv_t<<<dim3(1024/32, 3072/32), 256, 0, stream>>>(qkvw, wqkvt, 1024, 3072);
  wconv_t<<<dim3(1024/32, 1024/32), 256, 0, stream>>>(projw, wprojt, 1024, 1024);
  wconv_t<<<dim3(1024/32, 4096/32), 256, 0, stream>>>(ff1w, wff1t, 1024, 4096);
  wconv_t<<<dim3(4096/32, 1024/32), 256, 0, stream>>>(ff2w, wff2t, 4096, 1024);

  ln_fwd<<<MTOK, 256, 0, stream>>>(x, ln1g, ln1b, h1);

  gemm_bt<0><<<dim3(3072/128, MTOK/128), 256, 0, stream>>>(
      h1, wqkvt, qkvb, nullptr, nullptr, nullptr, qbuf, kbuf, vbuf, MTOK, 3072, 1024);

  attn_fwd<<<dim3(TT/64, BB*NHEADS), 256, 0, stream>>>(qbuf, kbuf, vbuf, aout);

  gemm_bt<1><<<dim3(1024/128, MTOK/128), 256, 0, stream>>>(
      aout, wprojt, projb, x, x2, nullptr, nullptr, nullptr, nullptr, MTOK, 1024, 1024);

  ln_fwd<<<MTOK, 256, 0, stream>>>(x2, ln2g, ln2b, h2);

  gemm_bt<2><<<dim3(4096/128, MTOK/128), 256, 0, stream>>>(
      h2, wff1t, ff1b, nullptr, nullptr, act, nullptr, nullptr, nullptr, MTOK, HID, 1024);

  gemm_bt<3><<<dim3(1024/128, MTOK/128), 256, 0, stream>>>(
      act, wff2t, ff2b, x2, out, nullptr, nullptr, nullptr, nullptr, MTOK, DIM, HID);
}

// Round 2
// 613.085 us; speedup vs baseline: 1.1490x; 1.1490x over previous
//
#include <hip/hip_runtime.h>
#include <hip/hip_bf16.h>
#include <math.h>

#define DIM 1024
#define NHEADS 16
#define HD 64
#define TT 2048
#define BB 4
#define MTOK (BB*TT)
#define HID 4096

typedef __attribute__((ext_vector_type(8))) short bf16x8;
typedef __attribute__((ext_vector_type(4))) float f32x4;
typedef unsigned short u16;

__device__ inline u16 f2b(float f){
  __hip_bfloat16 h = __float2bfloat16(f);
  return __builtin_bit_cast(u16, h);
}

__device__ inline void load_lds16(const void* g, void* l){
  __builtin_amdgcn_global_load_lds(
      (const __attribute__((address_space(1))) void*)g,
      (__attribute__((address_space(3))) void*)l,
      16, 0, 0);
}

// ---------------- weight transpose + f32->bf16 convert: Wt[n][k] = W[k][n]
__global__ __launch_bounds__(256) void wconv_t(const float* __restrict__ W,
                                               u16* __restrict__ Wt, int K, int N){
  __shared__ float tl[32][33];
  const int k0 = blockIdx.x*32, n0 = blockIdx.y*32;
  const int tx = threadIdx.x & 31, ty = threadIdx.x >> 5; // 32 x 8
  #pragma unroll
  for (int r=0;r<32;r+=8)
    tl[ty+r][tx] = W[(size_t)(k0+ty+r)*N + (n0+tx)];
  __syncthreads();
  #pragma unroll
  for (int r=0;r<32;r+=8)
    Wt[(size_t)(n0+ty+r)*K + (k0+tx)] = f2b(tl[tx][ty+r]);
}

// ---------------- layernorm: f32 in -> bf16 out
__global__ __launch_bounds__(256) void ln_fwd(const float* __restrict__ x,
                                              const float* __restrict__ g,
                                              const float* __restrict__ bta,
                                              u16* __restrict__ out){
  const int row = blockIdx.x, t = threadIdx.x;
  const float4 v = ((const float4*)(x + (size_t)row*DIM))[t];
  float s  = v.x+v.y+v.z+v.w;
  float s2 = v.x*v.x+v.y*v.y+v.z*v.z+v.w*v.w;
  #pragma unroll
  for (int m=1;m<64;m<<=1){ s += __shfl_xor(s,m); s2 += __shfl_xor(s2,m); }
  __shared__ float red[8];
  if ((t&63)==0){ red[t>>6]=s; red[4+(t>>6)]=s2; }
  __syncthreads();
  s  = red[0]+red[1]+red[2]+red[3];
  s2 = red[4]+red[5]+red[6]+red[7];
  const float mu = s*(1.0f/DIM);
  const float rstd = rsqrtf(s2*(1.0f/DIM) - mu*mu + 1e-5f);
  const float4 gv = ((const float4*)g)[t];
  const float4 bv = ((const float4*)bta)[t];
  ushort4 ov;
  ov.x = f2b((v.x-mu)*rstd*gv.x + bv.x);
  ov.y = f2b((v.y-mu)*rstd*gv.y + bv.y);
  ov.z = f2b((v.z-mu)*rstd*gv.z + bv.z);
  ov.w = f2b((v.w-mu)*rstd*gv.w + bv.w);
  ((ushort4*)out)[(size_t)row*(DIM/4) + t] = ov;
}

// ---------------- GEMM: C[M][N] = A[M][K](bf16) @ Bt[N][K](bf16)^T + bias, fused epilogues
// EPI 0: qkv split -> q [B,H,T,hd] / k [B,H,T,hd] / v^T [B,H,hd,T]  (bf16)
// EPI 1: + resid(f32) -> outf (x2)
// EPI 2: exact gelu -> outh (act, row stride HID)
// EPI 3: + resid(f32) -> outf (final out)
template<int EPI>
__global__ __launch_bounds__(256) void gemm_bt(
    const u16* __restrict__ A, const u16* __restrict__ Bt,
    const float* __restrict__ bias, const float* __restrict__ resid,
    float* __restrict__ outf, u16* __restrict__ outh,
    u16* __restrict__ qo, u16* __restrict__ ko, u16* __restrict__ vo,
    int M, int N, int K)
{
  __shared__ __align__(16) u16 As[128*32];
  __shared__ __align__(16) u16 Bs[128*32];
  const int t = threadIdx.x, wv = t>>6, ln = t&63;
  // bijective XCD-aware swizzle of the flattened block id (nwg % 8 == 0 for all our grids)
  const int nbx = gridDim.x, nwg = nbx*gridDim.y;
  const int bid = blockIdx.y*nbx + blockIdx.x;
  const int cpx = nwg>>3;
  const int wid = (bid&7)*cpx + (bid>>3);
  const int m0 = (wid/nbx)*128, n0 = (wid%nbx)*128;
  const int wr = wv>>1, wc = wv&1;
  const int lr = (ln>>4)*4, lc = ln&15, kb8 = (ln>>4)*8;
  f32x4 acc[4][4] = {};
  for (int kt=0; kt<K; kt+=32){
    #pragma unroll
    for (int j=0;j<2;j++){
      const int chunk = wv*2+j;
      const int byteoff = (chunk<<10) + (ln<<4);
      const int row = byteoff>>6;
      const int colb = byteoff&63;
      load_lds16((const char*)(A  + (size_t)(m0+row)*K + kt) + colb, (char*)As + (chunk<<10));
      load_lds16((const char*)(Bt + (size_t)(n0+row)*K + kt) + colb, (char*)Bs + (chunk<<10));
    }
    asm volatile("s_waitcnt vmcnt(0)" ::: "memory");
    __syncthreads();
    bf16x8 af[4], bfr[4];
    #pragma unroll
    for (int mi=0;mi<4;mi++)
      af[mi] = *(const bf16x8*)&As[(wr*64 + mi*16 + lc)*32 + kb8];
    #pragma unroll
    for (int ni=0;ni<4;ni++)
      bfr[ni] = *(const bf16x8*)&Bs[(wc*64 + ni*16 + lc)*32 + kb8];
    #pragma unroll
    for (int mi=0;mi<4;mi++)
      #pragma unroll
      for (int ni=0;ni<4;ni++)
        acc[mi][ni] = __builtin_amdgcn_mfma_f32_16x16x32_bf16(af[mi], bfr[ni], acc[mi][ni], 0,0,0);
    __syncthreads();
  }
  #pragma unroll
  for (int ni=0;ni<4;ni++){
    const int gn = n0 + wc*64 + ni*16 + lc;
    const float bv = bias[gn];
    #pragma unroll
    for (int mi=0;mi<4;mi++){
      const int gmb = m0 + wr*64 + mi*16 + lr;
      f32x4 a = acc[mi][ni];
      if constexpr (EPI==0){
        const int part = gn>>10, c = gn&1023;
        const int h = c>>6, d = c&63;
        const int bb = gmb>>11, tok0 = gmb&2047;
        if (part==2){
          ushort4 sv;
          sv.x = f2b(a[0]+bv); sv.y = f2b(a[1]+bv);
          sv.z = f2b(a[2]+bv); sv.w = f2b(a[3]+bv);
          *(ushort4*)&vo[(((size_t)bb*NHEADS + h)*HD + d)*TT + tok0] = sv;
        } else {
          u16* dst = part ? ko : qo;
          #pragma unroll
          for (int i=0;i<4;i++)
            dst[(((size_t)bb*NHEADS + h)*TT + tok0 + i)*HD + d] = f2b(a[i]+bv);
        }
      } else {
        #pragma unroll
        for (int i=0;i<4;i++){
          const int gm = gmb + i;
          float val = a[i] + bv;
          if constexpr (EPI==1){
            const size_t idx = (size_t)gm*DIM + gn;
            outf[idx] = val + resid[idx];
          } else if constexpr (EPI==2){
            const float gl = 0.5f*val*(1.0f + erff(val*0.70710678118654752f));
            outh[(size_t)gm*HID + gn] = f2b(gl);
          } else {
            const size_t idx = (size_t)gm*DIM + gn;
            outf[idx] = val + resid[idx];
          }
        }
      }
    }
  }
}

// ---------------- causal flash attention, one block per (qblock of 64, b*h)
// V comes in PRE-TRANSPOSED: vtb is [B,H,hd,T]
__global__ __launch_bounds__(256) void attn_fwd(
    const u16* __restrict__ qb, const u16* __restrict__ kb, const u16* __restrict__ vtb,
    u16* __restrict__ o)
{
  __shared__ __align__(16) u16 Ks[64*72];
  __shared__ __align__(16) u16 Vs[64*72];   // Vs[d][kv]
  __shared__ __align__(16) u16 Ps[4][16*72];
  const int t = threadIdx.x, wv = t>>6, ln = t&63;
  const int qblk = gridDim.x - 1 - blockIdx.x;  // heavy blocks first
  const int bh = blockIdx.y;
  const size_t base = (size_t)bh*TT*HD;
  const int lr = (ln>>4)*4, lc = ln&15, kb8 = (ln>>4)*8;
  const int qrow = qblk*64 + wv*16 + lc;
  const bf16x8 qf0 = *(const bf16x8*)(qb + base + (size_t)qrow*HD + kb8);
  const bf16x8 qf1 = *(const bf16x8*)(qb + base + (size_t)qrow*HD + 32 + kb8);
  f32x4 oacc[4] = {};
  float mrun[4] = {-1e30f,-1e30f,-1e30f,-1e30f};
  float lrun[4] = {0.f,0.f,0.f,0.f};
  const int qg0 = qblk*64 + wv*16 + lr;
  for (int kt=0; kt<=qblk; kt++){
    __syncthreads();
    #pragma unroll
    for (int j=0;j<2;j++){
      const int c = t + j*256;
      const int row = c>>3, ce = (c&7)*8;
      *(bf16x8*)&Ks[row*72 + ce] = *(const bf16x8*)(kb  + base + (size_t)(kt*64+row)*HD + ce);
      *(bf16x8*)&Vs[row*72 + ce] = *(const bf16x8*)(vtb + base + (size_t)row*TT + kt*64 + ce);
    }
    __syncthreads();
    f32x4 sf[4];
    #pragma unroll
    for (int cf=0;cf<4;cf++){
      const bf16x8 kf0 = *(const bf16x8*)&Ks[(cf*16+lc)*72 + kb8];
      const bf16x8 kf1 = *(const bf16x8*)&Ks[(cf*16+lc)*72 + 32 + kb8];
      f32x4 z = {0.f,0.f,0.f,0.f};
      z = __builtin_amdgcn_mfma_f32_16x16x32_bf16(qf0, kf0, z, 0,0,0);
      z = __builtin_amdgcn_mfma_f32_16x16x32_bf16(qf1, kf1, z, 0,0,0);
      sf[cf] = z;
    }
    float p[4][4];
    #pragma unroll
    for (int i=0;i<4;i++){
      const int qg = qg0 + i;
      float mx = -1e30f;
      #pragma unroll
      for (int cf=0;cf<4;cf++){
        const int kvg = kt*64 + cf*16 + lc;
        float sv = sf[cf][i]*0.125f;
        sv = (kvg > qg) ? -1e30f : sv;
        p[cf][i] = sv;
        mx = fmaxf(mx, sv);
      }
      #pragma unroll
      for (int msk=1;msk<16;msk<<=1) mx = fmaxf(mx, __shfl_xor(mx, msk));
      const float mnew = fmaxf(mrun[i], mx);
      const float sc = __expf(mrun[i] - mnew);
      float ssum = 0.f;
      #pragma unroll
      for (int cf=0;cf<4;cf++){
        const float pv = __expf(p[cf][i] - mnew);
        p[cf][i] = pv;
        ssum += pv;
      }
      #pragma unroll
      for (int msk=1;msk<16;msk<<=1) ssum += __shfl_xor(ssum, msk);
      lrun[i] = lrun[i]*sc + ssum;
      mrun[i] = mnew;
      #pragma unroll
      for (int df=0;df<4;df++) oacc[df][i] *= sc;
    }
    u16* pw = Ps[wv];
    #pragma unroll
    for (int cf=0;cf<4;cf++)
      #pragma unroll
      for (int i=0;i<4;i++)
        pw[(lr+i)*72 + cf*16 + lc] = f2b(p[cf][i]);
    const bf16x8 pa0 = *(const bf16x8*)&pw[lc*72 + kb8];
    const bf16x8 pa1 = *(const bf16x8*)&pw[lc*72 + 32 + kb8];
    #pragma unroll
    for (int df=0;df<4;df++){
      const bf16x8 v0 = *(const bf16x8*)&Vs[(df*16+lc)*72 + kb8];
      const bf16x8 v1 = *(const bf16x8*)&Vs[(df*16+lc)*72 + 32 + kb8];
      oacc[df] = __builtin_amdgcn_mfma_f32_16x16x32_bf16(pa0, v0, oacc[df], 0,0,0);
      oacc[df] = __builtin_amdgcn_mfma_f32_16x16x32_bf16(pa1, v1, oacc[df], 0,0,0);
    }
  }
  const int b = bh>>4, h = bh&15;
  #pragma unroll
  for (int i=0;i<4;i++){
    const float inv = 1.0f / lrun[i];
    const size_t rowb = ((size_t)b*TT + (size_t)(qg0 + i))*DIM + h*HD;
    #pragma unroll
    for (int df=0;df<4;df++)
      o[rowb + df*16 + lc] = f2b(oacc[df][i]*inv);
  }
}

extern "C" void kernel_launch(void* const* d_in, const int* in_sizes, int n_in,
                              void* d_out, int out_size, void* d_ws, size_t ws_size,
                              hipStream_t stream){
  (void)in_sizes; (void)n_in; (void)out_size; (void)ws_size;
  const float* x     = (const float*)d_in[0];
  const float* ln1g  = (const float*)d_in[1];
  const float* ln1b  = (const float*)d_in[2];
  const float* qkvw  = (const float*)d_in[3];
  const float* qkvb  = (const float*)d_in[4];
  const float* projw = (const float*)d_in[5];
  const float* projb = (const float*)d_in[6];
  const float* ln2g  = (const float*)d_in[7];
  const float* ln2b  = (const float*)d_in[8];
  const float* ff1w  = (const float*)d_in[9];
  const float* ff1b  = (const float*)d_in[10];
  const float* ff2w  = (const float*)d_in[11];
  const float* ff2b  = (const float*)d_in[12];
  float* out = (float*)d_out;

  char* ws = (char*)d_ws;
  size_t off = 0;
  auto alloc = [&](size_t n){ char* p = ws + off; off += (n + 255) & ~(size_t)255; return p; };
  u16* wqkvt  = (u16*)alloc((size_t)3072*1024*2);
  u16* wprojt = (u16*)alloc((size_t)1024*1024*2);
  u16* wff1t  = (u16*)alloc((size_t)4096*1024*2);
  u16* wff2t  = (u16*)alloc((size_t)1024*4096*2);
  u16* h1     = (u16*)alloc((size_t)MTOK*DIM*2);
  u16* qbuf   = (u16*)alloc((size_t)MTOK*DIM*2);
  u16* kbuf   = (u16*)alloc((size_t)MTOK*DIM*2);
  u16* vbuf   = (u16*)alloc((size_t)MTOK*DIM*2);   // [B,H,hd,T] transposed
  u16* aout   = (u16*)alloc((size_t)MTOK*DIM*2);
  float* x2   = (float*)alloc((size_t)MTOK*DIM*4);
  u16* h2     = (u16*)alloc((size_t)MTOK*DIM*2);
  u16* act    = (u16*)alloc((size_t)MTOK*HID*2);

  wconv_t<<<dim3(1024/32, 3072/32), 256, 0, stream>>>(qkvw, wqkvt, 1024, 3072);
  wconv_t<<<dim3(1024/32, 1024/32), 256, 0, stream>>>(projw, wprojt, 1024, 1024);
  wconv_t<<<dim3(1024/32, 4096/32), 256, 0, stream>>>(ff1w, wff1t, 1024, 4096);
  wconv_t<<<dim3(4096/32, 1024/32), 256, 0, stream>>>(ff2w, wff2t, 4096, 1024);

  ln_fwd<<<MTOK, 256, 0, stream>>>(x, ln1g, ln1b, h1);

  gemm_bt<0><<<dim3(3072/128, MTOK/128), 256, 0, stream>>>(
      h1, wqkvt, qkvb, nullptr, nullptr, nullptr, qbuf, kbuf, vbuf, MTOK, 3072, 1024);

  attn_fwd<<<dim3(TT/64, BB*NHEADS), 256, 0, stream>>>(qbuf, kbuf, vbuf, aout);

  gemm_bt<1><<<dim3(1024/128, MTOK/128), 256, 0, stream>>>(
      aout, wprojt, projb, x, x2, nullptr, nullptr, nullptr, nullptr, MTOK, 1024, 1024);

  ln_fwd<<<MTOK, 256, 0, stream>>>(x2, ln2g, ln2b, h2);

  gemm_bt<2><<<dim3(4096/128, MTOK/128), 256, 0, stream>>>(
      h2, wff1t, ff1b, nullptr, nullptr, act, nullptr, nullptr, nullptr, MTOK, HID, 1024);

  gemm_bt<3><<<dim3(1024/128, MTOK/128), 256, 0, stream>>>(
      act, wff2t, ff2b, x2, out, nullptr, nullptr, nullptr, nullptr, MTOK, DIM, HID);
}

// Round 3
// 579.143 us; speedup vs baseline: 1.2164x; 1.0586x over previous
//
#include <hip/hip_runtime.h>
#include <hip/hip_bf16.h>
#include <math.h>

#define DIM 1024
#define NHEADS 16
#define HD 64
#define TT 2048
#define BB 4
#define MTOK (BB*TT)
#define HID 4096

typedef __attribute__((ext_vector_type(8))) short bf16x8;
typedef __attribute__((ext_vector_type(4))) float f32x4;
typedef unsigned short u16;
typedef unsigned int u32;

__device__ inline u16 f2b(float f){
  __hip_bfloat16 h = __float2bfloat16(f);
  return __builtin_bit_cast(u16, h);
}

__device__ inline void load_lds16(const void* g, void* l){
  __builtin_amdgcn_global_load_lds(
      (const __attribute__((address_space(1))) void*)g,
      (__attribute__((address_space(3))) void*)l,
      16, 0, 0);
}

// ---------------- weight transpose + f32->bf16 convert: Wt[n][k] = W[k][n]
__global__ __launch_bounds__(256) void wconv_t(const float* __restrict__ W,
                                               u16* __restrict__ Wt, int K, int N){
  __shared__ float tl[32][33];
  const int k0 = blockIdx.x*32, n0 = blockIdx.y*32;
  const int tx = threadIdx.x & 31, ty = threadIdx.x >> 5; // 32 x 8
  #pragma unroll
  for (int r=0;r<32;r+=8)
    tl[ty+r][tx] = W[(size_t)(k0+ty+r)*N + (n0+tx)];
  __syncthreads();
  #pragma unroll
  for (int r=0;r<32;r+=8)
    Wt[(size_t)(n0+ty+r)*K + (k0+tx)] = f2b(tl[tx][ty+r]);
}

// ---------------- layernorm: f32 in -> bf16 out
__global__ __launch_bounds__(256) void ln_fwd(const float* __restrict__ x,
                                              const float* __restrict__ g,
                                              const float* __restrict__ bta,
                                              u16* __restrict__ out){
  const int row = blockIdx.x, t = threadIdx.x;
  const float4 v = ((const float4*)(x + (size_t)row*DIM))[t];
  float s  = v.x+v.y+v.z+v.w;
  float s2 = v.x*v.x+v.y*v.y+v.z*v.z+v.w*v.w;
  #pragma unroll
  for (int m=1;m<64;m<<=1){ s += __shfl_xor(s,m); s2 += __shfl_xor(s2,m); }
  __shared__ float red[8];
  if ((t&63)==0){ red[t>>6]=s; red[4+(t>>6)]=s2; }
  __syncthreads();
  s  = red[0]+red[1]+red[2]+red[3];
  s2 = red[4]+red[5]+red[6]+red[7];
  const float mu = s*(1.0f/DIM);
  const float rstd = rsqrtf(s2*(1.0f/DIM) - mu*mu + 1e-5f);
  const float4 gv = ((const float4*)g)[t];
  const float4 bv = ((const float4*)bta)[t];
  ushort4 ov;
  ov.x = f2b((v.x-mu)*rstd*gv.x + bv.x);
  ov.y = f2b((v.y-mu)*rstd*gv.y + bv.y);
  ov.z = f2b((v.z-mu)*rstd*gv.z + bv.z);
  ov.w = f2b((v.w-mu)*rstd*gv.w + bv.w);
  ((ushort4*)out)[(size_t)row*(DIM/4) + t] = ov;
}

// ---------------- GEMM: C[M][N] = A[M][K](bf16) @ Bt[N][K](bf16)^T + bias, fused epilogues
template<int EPI>
__global__ __launch_bounds__(256) void gemm_bt(
    const u16* __restrict__ A, const u16* __restrict__ Bt,
    const float* __restrict__ bias, const float* __restrict__ resid,
    float* __restrict__ outf, u16* __restrict__ outh,
    u16* __restrict__ qo, u16* __restrict__ ko, u16* __restrict__ vo,
    int M, int N, int K)
{
  __shared__ __align__(16) u16 As[128*32];
  __shared__ __align__(16) u16 Bs[128*32];
  const int t = threadIdx.x, wv = t>>6, ln = t&63;
  const int nbx = gridDim.x, nwg = nbx*gridDim.y;
  const int bid = blockIdx.y*nbx + blockIdx.x;
  const int cpx = nwg>>3;
  const int wid = (bid&7)*cpx + (bid>>3);
  const int m0 = (wid/nbx)*128, n0 = (wid%nbx)*128;
  const int wr = wv>>1, wc = wv&1;
  const int lr = (ln>>4)*4, lc = ln&15, kb8 = (ln>>4)*8;
  f32x4 acc[4][4] = {};
  for (int kt=0; kt<K; kt+=32){
    #pragma unroll
    for (int j=0;j<2;j++){
      const int chunk = wv*2+j;
      const int byteoff = (chunk<<10) + (ln<<4);
      const int row = byteoff>>6;
      const int colb = byteoff&63;
      load_lds16((const char*)(A  + (size_t)(m0+row)*K + kt) + colb, (char*)As + (chunk<<10));
      load_lds16((const char*)(Bt + (size_t)(n0+row)*K + kt) + colb, (char*)Bs + (chunk<<10));
    }
    asm volatile("s_waitcnt vmcnt(0)" ::: "memory");
    __syncthreads();
    bf16x8 af[4], bfr[4];
    #pragma unroll
    for (int mi=0;mi<4;mi++)
      af[mi] = *(const bf16x8*)&As[(wr*64 + mi*16 + lc)*32 + kb8];
    #pragma unroll
    for (int ni=0;ni<4;ni++)
      bfr[ni] = *(const bf16x8*)&Bs[(wc*64 + ni*16 + lc)*32 + kb8];
    #pragma unroll
    for (int mi=0;mi<4;mi++)
      #pragma unroll
      for (int ni=0;ni<4;ni++)
        acc[mi][ni] = __builtin_amdgcn_mfma_f32_16x16x32_bf16(af[mi], bfr[ni], acc[mi][ni], 0,0,0);
    __syncthreads();
  }
  #pragma unroll
  for (int ni=0;ni<4;ni++){
    const int gn = n0 + wc*64 + ni*16 + lc;
    const float bv = bias[gn];
    #pragma unroll
    for (int mi=0;mi<4;mi++){
      const int gmb = m0 + wr*64 + mi*16 + lr;
      f32x4 a = acc[mi][ni];
      if constexpr (EPI==0){
        const int part = gn>>10, c = gn&1023;
        const int h = c>>6, d = c&63;
        const int bb = gmb>>11, tok0 = gmb&2047;
        if (part==2){
          ushort4 sv;
          sv.x = f2b(a[0]+bv); sv.y = f2b(a[1]+bv);
          sv.z = f2b(a[2]+bv); sv.w = f2b(a[3]+bv);
          *(ushort4*)&vo[(((size_t)bb*NHEADS + h)*HD + d)*TT + tok0] = sv;
        } else {
          u16* dst = part ? ko : qo;
          #pragma unroll
          for (int i=0;i<4;i++)
            dst[(((size_t)bb*NHEADS + h)*TT + tok0 + i)*HD + d] = f2b(a[i]+bv);
        }
      } else {
        #pragma unroll
        for (int i=0;i<4;i++){
          const int gm = gmb + i;
          float val = a[i] + bv;
          if constexpr (EPI==1){
            const size_t idx = (size_t)gm*DIM + gn;
            outf[idx] = val + resid[idx];
          } else if constexpr (EPI==2){
            const float gl = 0.5f*val*(1.0f + erff(val*0.70710678118654752f));
            outh[(size_t)gm*HID + gn] = f2b(gl);
          } else {
            const size_t idx = (size_t)gm*DIM + gn;
            outf[idx] = val + resid[idx];
          }
        }
      }
    }
  }
}

// ---------------- causal flash attention (swapped QK^T, in-register softmax)
// V comes in PRE-TRANSPOSED: vtb is [B,H,hd,T]
__global__ __launch_bounds__(256) void attn_fwd(
    const u16* __restrict__ qb, const u16* __restrict__ kb, const u16* __restrict__ vtb,
    u16* __restrict__ o)
{
  __shared__ __align__(16) u16 Ks[64*72];
  __shared__ __align__(16) u16 Vs[64*72];   // Vs[d][kv]
  __shared__ __align__(16) u32 Ps[4][16*40]; // per-wave P[q][kv/2], stride 40 dwords
  const int t = threadIdx.x, wv = t>>6, ln = t&63;
  const int qblk = gridDim.x - 1 - blockIdx.x;  // heavy blocks first
  const int bh = blockIdx.y;
  const size_t base = (size_t)bh*TT*HD;
  const int hi = ln>>4, lc = ln&15, kb8 = hi*8;
  const int qrow = qblk*64 + wv*16 + lc;   // softmax q owned by this lane
  const bf16x8 qf0 = *(const bf16x8*)(qb + base + (size_t)qrow*HD + kb8);
  const bf16x8 qf1 = *(const bf16x8*)(qb + base + (size_t)qrow*HD + 32 + kb8);
  f32x4 oacc[4] = {};
  float mrun = -1e30f, lrun = 0.f;
  const float SC = 0.125f * 1.44269504f;   // 1/sqrt(64) * log2(e): exp2 domain
  u32* pw = Ps[wv];
  const int qg0 = qblk*64 + wv*16 + 4*hi;  // PV-output q base for this lane

  for (int kt=0; kt<=qblk; kt++){
    __syncthreads();
    #pragma unroll
    for (int j=0;j<2;j++){
      const int c = t + j*256;
      const int row = c>>3, ce = (c&7)*8;
      *(bf16x8*)&Ks[row*72 + ce] = *(const bf16x8*)(kb  + base + (size_t)(kt*64+row)*HD + ce);
      *(bf16x8*)&Vs[row*72 + ce] = *(const bf16x8*)(vtb + base + (size_t)row*TT + kt*64 + ce);
    }
    __syncthreads();

    // swapped QK^T: D[row=kv][col=q]; lane holds kv = cf*16 + 4*hi + i for q=lc
    float p[4][4];
    float mx = -1e30f;
    #pragma unroll
    for (int cf=0;cf<4;cf++){
      const bf16x8 kf0 = *(const bf16x8*)&Ks[(cf*16+lc)*72 + kb8];
      const bf16x8 kf1 = *(const bf16x8*)&Ks[(cf*16+lc)*72 + 32 + kb8];
      f32x4 z = {0.f,0.f,0.f,0.f};
      z = __builtin_amdgcn_mfma_f32_16x16x32_bf16(kf0, qf0, z, 0,0,0);
      z = __builtin_amdgcn_mfma_f32_16x16x32_bf16(kf1, qf1, z, 0,0,0);
      #pragma unroll
      for (int i=0;i<4;i++){
        const int kvg = kt*64 + cf*16 + 4*hi + i;
        float sv = z[i]*SC;
        sv = (kvg > qrow) ? -1e30f : sv;
        p[cf][i] = sv;
        mx = fmaxf(mx, sv);
      }
    }
    // full-64kv max for q=lc: 2 shuffles across the hi groups
    mx = fmaxf(mx, __shfl_xor(mx, 16));
    mx = fmaxf(mx, __shfl_xor(mx, 32));

    // defer-max: only rescale when max grew materially (log2 domain, thr ~ 8 nats)
    if (__any(mx > mrun + 11.0f)){
      const float mnew = fmaxf(mrun, mx);
      const float sc = exp2f(mrun - mnew);
      mrun = mnew;
      lrun *= sc;
      const float s0 = __shfl(sc, 4*hi+0);
      const float s1 = __shfl(sc, 4*hi+1);
      const float s2 = __shfl(sc, 4*hi+2);
      const float s3 = __shfl(sc, 4*hi+3);
      #pragma unroll
      for (int df=0;df<4;df++){
        oacc[df][0] *= s0; oacc[df][1] *= s1;
        oacc[df][2] *= s2; oacc[df][3] *= s3;
      }
    }

    float ssum = 0.f;
    #pragma unroll
    for (int cf=0;cf<4;cf++)
      #pragma unroll
      for (int i=0;i<4;i++){
        const float pv = exp2f(p[cf][i] - mrun);
        p[cf][i] = pv;
        ssum += pv;
      }
    ssum += __shfl_xor(ssum, 16);
    ssum += __shfl_xor(ssum, 32);
    lrun += ssum;

    // pack P -> per-wave LDS [q=lc][kv dwords]: 8 dword writes
    #pragma unroll
    for (int cf=0;cf<4;cf++){
      const u32 w0 = (u32)f2b(p[cf][0]) | ((u32)f2b(p[cf][1])<<16);
      const u32 w1 = (u32)f2b(p[cf][2]) | ((u32)f2b(p[cf][3])<<16);
      pw[lc*40 + cf*8 + 2*hi + 0] = w0;
      pw[lc*40 + cf*8 + 2*hi + 1] = w1;
    }
    asm volatile("s_waitcnt lgkmcnt(0)" ::: "memory");

    // PV: A-frag = P[q=lc][kv=8hi..], B-frag = V^T[d=lc][kv=8hi..]
    const bf16x8 pa0 = *(const bf16x8*)&pw[lc*40 + 4*hi];
    const bf16x8 pa1 = *(const bf16x8*)&pw[lc*40 + 16 + 4*hi];
    #pragma unroll
    for (int df=0;df<4;df++){
      const bf16x8 v0 = *(const bf16x8*)&Vs[(df*16+lc)*72 + kb8];
      const bf16x8 v1 = *(const bf16x8*)&Vs[(df*16+lc)*72 + 32 + kb8];
      oacc[df] = __builtin_amdgcn_mfma_f32_16x16x32_bf16(pa0, v0, oacc[df], 0,0,0);
      oacc[df] = __builtin_amdgcn_mfma_f32_16x16x32_bf16(pa1, v1, oacc[df], 0,0,0);
    }
  }

  // O-normalize: lane's output rows are q = qg0 + i; pull 1/l from softmax lanes
  const float l0 = __shfl(lrun, 4*hi+0);
  const float l1 = __shfl(lrun, 4*hi+1);
  const float l2 = __shfl(lrun, 4*hi+2);
  const float l3 = __shfl(lrun, 4*hi+3);
  const float inv[4] = {1.0f/l0, 1.0f/l1, 1.0f/l2, 1.0f/l3};
  const int b = bh>>4, h = bh&15;
  #pragma unroll
  for (int i=0;i<4;i++){
    const size_t rowb = ((size_t)b*TT + (size_t)(qg0 + i))*DIM + h*HD;
    #pragma unroll
    for (int df=0;df<4;df++)
      o[rowb + df*16 + lc] = f2b(oacc[df][i]*inv[i]);
  }
}

extern "C" void kernel_launch(void* const* d_in, const int* in_sizes, int n_in,
                              void* d_out, int out_size, void* d_ws, size_t ws_size,
                              hipStream_t stream){
  (void)in_sizes; (void)n_in; (void)out_size; (void)ws_size;
  const float* x     = (const float*)d_in[0];
  const float* ln1g  = (const float*)d_in[1];
  const float* ln1b  = (const float*)d_in[2];
  const float* qkvw  = (const float*)d_in[3];
  const float* qkvb  = (const float*)d_in[4];
  const float* projw = (const float*)d_in[5];
  const float* projb = (const float*)d_in[6];
  const float* ln2g  = (const float*)d_in[7];
  const float* ln2b  = (const float*)d_in[8];
  const float* ff1w  = (const float*)d_in[9];
  const float* ff1b  = (const float*)d_in[10];
  const float* ff2w  = (const float*)d_in[11];
  const float* ff2b  = (const float*)d_in[12];
  float* out = (float*)d_out;

  char* ws = (char*)d_ws;
  size_t off = 0;
  auto alloc = [&](size_t n){ char* p = ws + off; off += (n + 255) & ~(size_t)255; return p; };
  u16* wqkvt  = (u16*)alloc((size_t)3072*1024*2);
  u16* wprojt = (u16*)alloc((size_t)1024*1024*2);
  u16* wff1t  = (u16*)alloc((size_t)4096*1024*2);
  u16* wff2t  = (u16*)alloc((size_t)1024*4096*2);
  u16* h1     = (u16*)alloc((size_t)MTOK*DIM*2);
  u16* qbuf   = (u16*)alloc((size_t)MTOK*DIM*2);
  u16* kbuf   = (u16*)alloc((size_t)MTOK*DIM*2);
  u16* vbuf   = (u16*)alloc((size_t)MTOK*DIM*2);   // [B,H,hd,T] transposed
  u16* aout   = (u16*)alloc((size_t)MTOK*DIM*2);
  float* x2   = (float*)alloc((size_t)MTOK*DIM*4);
  u16* h2     = (u16*)alloc((size_t)MTOK*DIM*2);
  u16* act    = (u16*)alloc((size_t)MTOK*HID*2);

  wconv_t<<<dim3(1024/32, 3072/32), 256, 0, stream>>>(qkvw, wqkvt, 1024, 3072);
  wconv_t<<<dim3(1024/32, 1024/32), 256, 0, stream>>>(projw, wprojt, 1024, 1024);
  wconv_t<<<dim3(1024/32, 4096/32), 256, 0, stream>>>(ff1w, wff1t, 1024, 4096);
  wconv_t<<<dim3(4096/32, 1024/32), 256, 0, stream>>>(ff2w, wff2t, 4096, 1024);

  ln_fwd<<<MTOK, 256, 0, stream>>>(x, ln1g, ln1b, h1);

  gemm_bt<0><<<dim3(3072/128, MTOK/128), 256, 0, stream>>>(
      h1, wqkvt, qkvb, nullptr, nullptr, nullptr, qbuf, kbuf, vbuf, MTOK, 3072, 1024);

  attn_fwd<<<dim3(TT/64, BB*NHEADS), 256, 0, stream>>>(qbuf, kbuf, vbuf, aout);

  gemm_bt<1><<<dim3(1024/128, MTOK/128), 256, 0, stream>>>(
      aout, wprojt, projb, x, x2, nullptr, nullptr, nullptr, nullptr, MTOK, 1024, 1024);

  ln_fwd<<<MTOK, 256, 0, stream>>>(x2, ln2g, ln2b, h2);

  gemm_bt<2><<<dim3(4096/128, MTOK/128), 256, 0, stream>>>(
      h2, wff1t, ff1b, nullptr, nullptr, act, nullptr, nullptr, nullptr, MTOK, HID, 1024);

  gemm_bt<3><<<dim3(1024/128, MTOK/128), 256, 0, stream>>>(
      act, wff2t, ff2b, x2, out, nullptr, nullptr, nullptr, nullptr, MTOK, DIM, HID);
}

// Round 4
// 548.482 us; speedup vs baseline: 1.2844x; 1.0559x over previous
//
#include <hip/hip_runtime.h>
#include <hip/hip_bf16.h>
#include <math.h>

#define DIM 1024
#define NHEADS 16
#define HD 64
#define TT 2048
#define BB 4
#define MTOK (BB*TT)
#define HID 4096

typedef __attribute__((ext_vector_type(8))) short bf16x8;
typedef __attribute__((ext_vector_type(4))) float f32x4;
typedef unsigned short u16;
typedef unsigned int u32;

__device__ inline u16 f2b(float f){
  __hip_bfloat16 h = __float2bfloat16(f);
  return __builtin_bit_cast(u16, h);
}

__device__ inline void load_lds16(const void* g, void* l){
  __builtin_amdgcn_global_load_lds(
      (const __attribute__((address_space(1))) void*)g,
      (__attribute__((address_space(3))) void*)l,
      16, 0, 0);
}

// ---------------- weight transpose + f32->bf16 convert: Wt[n][k] = W[k][n]
__global__ __launch_bounds__(256) void wconv_t(const float* __restrict__ W,
                                               u16* __restrict__ Wt, int K, int N){
  __shared__ float tl[32][33];
  const int k0 = blockIdx.x*32, n0 = blockIdx.y*32;
  const int tx = threadIdx.x & 31, ty = threadIdx.x >> 5; // 32 x 8
  #pragma unroll
  for (int r=0;r<32;r+=8)
    tl[ty+r][tx] = W[(size_t)(k0+ty+r)*N + (n0+tx)];
  __syncthreads();
  #pragma unroll
  for (int r=0;r<32;r+=8)
    Wt[(size_t)(n0+ty+r)*K + (k0+tx)] = f2b(tl[tx][ty+r]);
}

// ---------------- layernorm: f32 in -> bf16 out
__global__ __launch_bounds__(256) void ln_fwd(const float* __restrict__ x,
                                              const float* __restrict__ g,
                                              const float* __restrict__ bta,
                                              u16* __restrict__ out){
  const int row = blockIdx.x, t = threadIdx.x;
  const float4 v = ((const float4*)(x + (size_t)row*DIM))[t];
  float s  = v.x+v.y+v.z+v.w;
  float s2 = v.x*v.x+v.y*v.y+v.z*v.z+v.w*v.w;
  #pragma unroll
  for (int m=1;m<64;m<<=1){ s += __shfl_xor(s,m); s2 += __shfl_xor(s2,m); }
  __shared__ float red[8];
  if ((t&63)==0){ red[t>>6]=s; red[4+(t>>6)]=s2; }
  __syncthreads();
  s  = red[0]+red[1]+red[2]+red[3];
  s2 = red[4]+red[5]+red[6]+red[7];
  const float mu = s*(1.0f/DIM);
  const float rstd = rsqrtf(s2*(1.0f/DIM) - mu*mu + 1e-5f);
  const float4 gv = ((const float4*)g)[t];
  const float4 bv = ((const float4*)bta)[t];
  ushort4 ov;
  ov.x = f2b((v.x-mu)*rstd*gv.x + bv.x);
  ov.y = f2b((v.y-mu)*rstd*gv.y + bv.y);
  ov.z = f2b((v.z-mu)*rstd*gv.z + bv.z);
  ov.w = f2b((v.w-mu)*rstd*gv.w + bv.w);
  ((ushort4*)out)[(size_t)row*(DIM/4) + t] = ov;
}

// ---------------- GEMM: C[M][N] = A[M][K](bf16) @ Bt[N][K](bf16)^T + bias, fused epilogues
template<int EPI>
__global__ __launch_bounds__(256) void gemm_bt(
    const u16* __restrict__ A, const u16* __restrict__ Bt,
    const float* __restrict__ bias, const float* __restrict__ resid,
    float* __restrict__ outf, u16* __restrict__ outh,
    u16* __restrict__ qo, u16* __restrict__ ko, u16* __restrict__ vo,
    int M, int N, int K)
{
  __shared__ __align__(16) u16 As[128*32];
  __shared__ __align__(16) u16 Bs[128*32];
  const int t = threadIdx.x, wv = t>>6, ln = t&63;
  const int nbx = gridDim.x, nwg = nbx*gridDim.y;
  const int bid = blockIdx.y*nbx + blockIdx.x;
  const int cpx = nwg>>3;
  const int wid = (bid&7)*cpx + (bid>>3);
  const int m0 = (wid/nbx)*128, n0 = (wid%nbx)*128;
  const int wr = wv>>1, wc = wv&1;
  const int lr = (ln>>4)*4, lc = ln&15, kb8 = (ln>>4)*8;
  f32x4 acc[4][4] = {};
  for (int kt=0; kt<K; kt+=32){
    #pragma unroll
    for (int j=0;j<2;j++){
      const int chunk = wv*2+j;
      const int byteoff = (chunk<<10) + (ln<<4);
      const int row = byteoff>>6;
      const int colb = byteoff&63;
      load_lds16((const char*)(A  + (size_t)(m0+row)*K + kt) + colb, (char*)As + (chunk<<10));
      load_lds16((const char*)(Bt + (size_t)(n0+row)*K + kt) + colb, (char*)Bs + (chunk<<10));
    }
    asm volatile("s_waitcnt vmcnt(0)" ::: "memory");
    __syncthreads();
    bf16x8 af[4], bfr[4];
    #pragma unroll
    for (int mi=0;mi<4;mi++)
      af[mi] = *(const bf16x8*)&As[(wr*64 + mi*16 + lc)*32 + kb8];
    #pragma unroll
    for (int ni=0;ni<4;ni++)
      bfr[ni] = *(const bf16x8*)&Bs[(wc*64 + ni*16 + lc)*32 + kb8];
    #pragma unroll
    for (int mi=0;mi<4;mi++)
      #pragma unroll
      for (int ni=0;ni<4;ni++)
        acc[mi][ni] = __builtin_amdgcn_mfma_f32_16x16x32_bf16(af[mi], bfr[ni], acc[mi][ni], 0,0,0);
    __syncthreads();
  }
  #pragma unroll
  for (int ni=0;ni<4;ni++){
    const int gn = n0 + wc*64 + ni*16 + lc;
    const float bv = bias[gn];
    #pragma unroll
    for (int mi=0;mi<4;mi++){
      const int gmb = m0 + wr*64 + mi*16 + lr;
      f32x4 a = acc[mi][ni];
      if constexpr (EPI==0){
        const int part = gn>>10, c = gn&1023;
        const int h = c>>6, d = c&63;
        const int bb = gmb>>11, tok0 = gmb&2047;
        if (part==2){
          ushort4 sv;
          sv.x = f2b(a[0]+bv); sv.y = f2b(a[1]+bv);
          sv.z = f2b(a[2]+bv); sv.w = f2b(a[3]+bv);
          *(ushort4*)&vo[(((size_t)bb*NHEADS + h)*HD + d)*TT + tok0] = sv;
        } else {
          u16* dst = part ? ko : qo;
          #pragma unroll
          for (int i=0;i<4;i++)
            dst[(((size_t)bb*NHEADS + h)*TT + tok0 + i)*HD + d] = f2b(a[i]+bv);
        }
      } else {
        #pragma unroll
        for (int i=0;i<4;i++){
          const int gm = gmb + i;
          float val = a[i] + bv;
          if constexpr (EPI==1){
            const size_t idx = (size_t)gm*DIM + gn;
            outf[idx] = val + resid[idx];
          } else if constexpr (EPI==2){
            const float gl = 0.5f*val*(1.0f + erff(val*0.70710678118654752f));
            outh[(size_t)gm*HID + gn] = f2b(gl);
          } else {
            const size_t idx = (size_t)gm*DIM + gn;
            outf[idx] = val + resid[idx];
          }
        }
      }
    }
  }
}

// ---------------- causal flash attention: QBLK=128, 2-phase prefetch, swizzled LDS
// V pre-transposed: vtb is [B,H,hd,T].  Grid: x=16 (qb), y=64 (bh), remapped.
__global__ __launch_bounds__(256) void attn_fwd(
    const u16* __restrict__ qpt, const u16* __restrict__ kb, const u16* __restrict__ vtb,
    u16* __restrict__ o)
{
  __shared__ __align__(16) u16 Kd[2][64*64];
  __shared__ __align__(16) u16 Vd[2][64*64];
  __shared__ __align__(16) u32 Ps[4][32*40];
  const int t = threadIdx.x, wv = t>>6, ln = t&63;
  // XCD-bijective remap: all 16 qb-blocks of 8 heads land on one XCD
  const int bid  = blockIdx.y*gridDim.x + blockIdx.x;      // 0..1023
  const int orig = (bid&7)*128 + (bid>>3);
  const int bh   = orig>>4;
  const int qb   = 15 - (orig&15);                          // heavy-first
  const size_t base = (size_t)bh*TT*HD;
  const int hi = ln>>4, lc = ln&15;
  const int nt = 2*qb + 2;

  // Q fragments for both 64-row groups (g=0,1)
  bf16x8 qf[2][2];
  #pragma unroll
  for (int g=0; g<2; g++){
    const int qrow = qb*128 + g*64 + wv*16 + lc;
    qf[g][0] = *(const bf16x8*)(qpt + base + (size_t)qrow*HD + hi*8);
    qf[g][1] = *(const bf16x8*)(qpt + base + (size_t)qrow*HD + 32 + hi*8);
  }
  f32x4 oacc[2][4] = {};
  float mrun[2] = {-1e30f,-1e30f}, lrun[2] = {0.f,0.f};
  const float SCQ = 0.125f * 1.44269504f;  // 1/sqrt(64)*log2e
  u32* pw = Ps[wv];
  const int srcch = ((ln&7) ^ (ln>>3)) << 3;   // pre-swizzled global chunk (elements)

  auto STAGE = [&](int nb, int kt){
    #pragma unroll
    for (int j=0;j<2;j++){
      const int row = j*32 + wv*8 + (ln>>3);
      load_lds16(kb  + base + (size_t)(kt*64+row)*HD + srcch, &Kd[nb][(j*32+wv*8)*64]);
      load_lds16(vtb + base + (size_t)row*TT + kt*64 + srcch, &Vd[nb][(j*32+wv*8)*64]);
    }
  };
  auto FRAG = [&](const u16* buf, int r, int ch)->bf16x8{
    return *(const bf16x8*)(buf + r*64 + ((ch ^ (r&7))<<3));
  };

  int cur = 0;
  STAGE(0, 0);
  asm volatile("s_waitcnt vmcnt(0)" ::: "memory");
  __syncthreads();

  for (int kt=0; kt<nt; kt++){
    if (kt+1 < nt) STAGE(cur^1, kt+1);
    const u16* Kb = Kd[cur];
    const u16* Vb = Vd[cur];
    #pragma unroll
    for (int g=0; g<2; g++){
      const int qmax = qb*128 + g*64 + wv*16 + 15;
      if (kt*64 > qmax) continue;              // fully masked sub-tile
      const int qrow = qb*128 + g*64 + wv*16 + lc;
      float p[4][4];
      float mx = -1e30f;
      #pragma unroll
      for (int cf=0;cf<4;cf++){
        const int r = cf*16 + lc;
        const bf16x8 kf0 = FRAG(Kb, r, hi);
        const bf16x8 kf1 = FRAG(Kb, r, hi+4);
        f32x4 z = {0.f,0.f,0.f,0.f};
        z = __builtin_amdgcn_mfma_f32_16x16x32_bf16(kf0, qf[g][0], z, 0,0,0);
        z = __builtin_amdgcn_mfma_f32_16x16x32_bf16(kf1, qf[g][1], z, 0,0,0);
        #pragma unroll
        for (int i=0;i<4;i++){
          const int kvg = kt*64 + cf*16 + 4*hi + i;
          float sv = z[i]*SCQ;
          sv = (kvg > qrow) ? -1e30f : sv;
          p[cf][i] = sv;
          mx = fmaxf(mx, sv);
        }
      }
      mx = fmaxf(mx, __shfl_xor(mx, 16));
      mx = fmaxf(mx, __shfl_xor(mx, 32));
      if (__any(mx > mrun[g] + 11.0f)){
        const float mnew = fmaxf(mrun[g], mx);
        const float sc = exp2f(mrun[g] - mnew);
        mrun[g] = mnew;
        lrun[g] *= sc;
        const float s0 = __shfl(sc, 4*hi+0);
        const float s1 = __shfl(sc, 4*hi+1);
        const float s2 = __shfl(sc, 4*hi+2);
        const float s3 = __shfl(sc, 4*hi+3);
        #pragma unroll
        for (int df=0;df<4;df++){
          oacc[g][df][0] *= s0; oacc[g][df][1] *= s1;
          oacc[g][df][2] *= s2; oacc[g][df][3] *= s3;
        }
      }
      float ssum = 0.f;
      #pragma unroll
      for (int cf=0;cf<4;cf++)
        #pragma unroll
        for (int i=0;i<4;i++){
          const float pv = exp2f(p[cf][i] - mrun[g]);
          p[cf][i] = pv;
          ssum += pv;
        }
      ssum += __shfl_xor(ssum, 16);
      ssum += __shfl_xor(ssum, 32);
      lrun[g] += ssum;
      const int prow = g*16 + lc;
      #pragma unroll
      for (int cf=0;cf<4;cf++){
        const u32 w0 = (u32)f2b(p[cf][0]) | ((u32)f2b(p[cf][1])<<16);
        const u32 w1 = (u32)f2b(p[cf][2]) | ((u32)f2b(p[cf][3])<<16);
        pw[prow*40 + cf*8 + 2*hi + 0] = w0;
        pw[prow*40 + cf*8 + 2*hi + 1] = w1;
      }
      asm volatile("s_waitcnt lgkmcnt(0)" ::: "memory");
      const bf16x8 pa0 = *(const bf16x8*)&pw[prow*40 - (lc-((ln&15)))*0 + (g*16+lc)*0 + 0];
      (void)pa0;
      const bf16x8 paA = *(const bf16x8*)&pw[(g*16+lc)*40 + 4*hi];
      const bf16x8 paB = *(const bf16x8*)&pw[(g*16+lc)*40 + 16 + 4*hi];
      #pragma unroll
      for (int df=0;df<4;df++){
        const bf16x8 v0 = FRAG(Vb, df*16+lc, hi);
        const bf16x8 v1 = FRAG(Vb, df*16+lc, hi+4);
        oacc[g][df] = __builtin_amdgcn_mfma_f32_16x16x32_bf16(paA, v0, oacc[g][df], 0,0,0);
        oacc[g][df] = __builtin_amdgcn_mfma_f32_16x16x32_bf16(paB, v1, oacc[g][df], 0,0,0);
      }
    }
    asm volatile("s_waitcnt vmcnt(0)" ::: "memory");
    __syncthreads();
    cur ^= 1;
  }

  const int b = bh>>4, h = bh&15;
  #pragma unroll
  for (int g=0; g<2; g++){
    const float l0 = __shfl(lrun[g], 4*hi+0);
    const float l1 = __shfl(lrun[g], 4*hi+1);
    const float l2 = __shfl(lrun[g], 4*hi+2);
    const float l3 = __shfl(lrun[g], 4*hi+3);
    const float inv[4] = {1.0f/l0, 1.0f/l1, 1.0f/l2, 1.0f/l3};
    const int qg0 = qb*128 + g*64 + wv*16 + 4*hi;
    #pragma unroll
    for (int i=0;i<4;i++){
      const size_t rowb = ((size_t)b*TT + (size_t)(qg0 + i))*DIM + h*HD;
      #pragma unroll
      for (int df=0;df<4;df++)
        o[rowb + df*16 + lc] = f2b(oacc[g][df][i]*inv[i]);
    }
  }
}

extern "C" void kernel_launch(void* const* d_in, const int* in_sizes, int n_in,
                              void* d_out, int out_size, void* d_ws, size_t ws_size,
                              hipStream_t stream){
  (void)in_sizes; (void)n_in; (void)out_size; (void)ws_size;
  const float* x     = (const float*)d_in[0];
  const float* ln1g  = (const float*)d_in[1];
  const float* ln1b  = (const float*)d_in[2];
  const float* qkvw  = (const float*)d_in[3];
  const float* qkvb  = (const float*)d_in[4];
  const float* projw = (const float*)d_in[5];
  const float* projb = (const float*)d_in[6];
  const float* ln2g  = (const float*)d_in[7];
  const float* ln2b  = (const float*)d_in[8];
  const float* ff1w  = (const float*)d_in[9];
  const float* ff1b  = (const float*)d_in[10];
  const float* ff2w  = (const float*)d_in[11];
  const float* ff2b  = (const float*)d_in[12];
  float* out = (float*)d_out;

  char* ws = (char*)d_ws;
  size_t off = 0;
  auto alloc = [&](size_t n){ char* p = ws + off; off += (n + 255) & ~(size_t)255; return p; };
  u16* wqkvt  = (u16*)alloc((size_t)3072*1024*2);
  u16* wprojt = (u16*)alloc((size_t)1024*1024*2);
  u16* wff1t  = (u16*)alloc((size_t)4096*1024*2);
  u16* wff2t  = (u16*)alloc((size_t)1024*4096*2);
  u16* h1     = (u16*)alloc((size_t)MTOK*DIM*2);
  u16* qbuf   = (u16*)alloc((size_t)MTOK*DIM*2);
  u16* kbuf   = (u16*)alloc((size_t)MTOK*DIM*2);
  u16* vbuf   = (u16*)alloc((size_t)MTOK*DIM*2);   // [B,H,hd,T] transposed
  u16* aout   = (u16*)alloc((size_t)MTOK*DIM*2);
  float* x2   = (float*)alloc((size_t)MTOK*DIM*4);
  u16* h2     = (u16*)alloc((size_t)MTOK*DIM*2);
  u16* act    = (u16*)alloc((size_t)MTOK*HID*2);

  wconv_t<<<dim3(1024/32, 3072/32), 256, 0, stream>>>(qkvw, wqkvt, 1024, 3072);
  wconv_t<<<dim3(1024/32, 1024/32), 256, 0, stream>>>(projw, wprojt, 1024, 1024);
  wconv_t<<<dim3(1024/32, 4096/32), 256, 0, stream>>>(ff1w, wff1t, 1024, 4096);
  wconv_t<<<dim3(4096/32, 1024/32), 256, 0, stream>>>(ff2w, wff2t, 4096, 1024);

  ln_fwd<<<MTOK, 256, 0, stream>>>(x, ln1g, ln1b, h1);

  gemm_bt<0><<<dim3(3072/128, MTOK/128), 256, 0, stream>>>(
      h1, wqkvt, qkvb, nullptr, nullptr, nullptr, qbuf, kbuf, vbuf, MTOK, 3072, 1024);

  attn_fwd<<<dim3(TT/128, BB*NHEADS), 256, 0, stream>>>(qbuf, kbuf, vbuf, aout);

  gemm_bt<1><<<dim3(1024/128, MTOK/128), 256, 0, stream>>>(
      aout, wprojt, projb, x, x2, nullptr, nullptr, nullptr, nullptr, MTOK, 1024, 1024);

  ln_fwd<<<MTOK, 256, 0, stream>>>(x2, ln2g, ln2b, h2);

  gemm_bt<2><<<dim3(4096/128, MTOK/128), 256, 0, stream>>>(
      h2, wff1t, ff1b, nullptr, nullptr, act, nullptr, nullptr, nullptr, MTOK, HID, 1024);

  gemm_bt<3><<<dim3(1024/128, MTOK/128), 256, 0, stream>>>(
      act, wff2t, ff2b, x2, out, nullptr, nullptr, nullptr, nullptr, MTOK, DIM, HID);
}

// Round 5
// 520.283 us; speedup vs baseline: 1.3540x; 1.0542x over previous
//
#include <hip/hip_runtime.h>
#include <hip/hip_bf16.h>
#include <math.h>

#define DIM 1024
#define NHEADS 16
#define HD 64
#define TT 2048
#define BB 4
#define MTOK (BB*TT)
#define HID 4096

typedef __attribute__((ext_vector_type(8))) short bf16x8;
typedef __attribute__((ext_vector_type(4))) float f32x4;
typedef unsigned short u16;
typedef unsigned int u32;

__device__ inline u16 f2b(float f){
  __hip_bfloat16 h = __float2bfloat16(f);
  return __builtin_bit_cast(u16, h);
}

__device__ inline void load_lds16(const void* g, void* l){
  __builtin_amdgcn_global_load_lds(
      (const __attribute__((address_space(1))) void*)g,
      (__attribute__((address_space(3))) void*)l,
      16, 0, 0);
}

// ---------------- weight transpose + f32->bf16 convert: Wt[n][k] = W[k][n]
__global__ __launch_bounds__(256) void wconv_t(const float* __restrict__ W,
                                               u16* __restrict__ Wt, int K, int N){
  __shared__ float tl[32][33];
  const int k0 = blockIdx.x*32, n0 = blockIdx.y*32;
  const int tx = threadIdx.x & 31, ty = threadIdx.x >> 5; // 32 x 8
  #pragma unroll
  for (int r=0;r<32;r+=8)
    tl[ty+r][tx] = W[(size_t)(k0+ty+r)*N + (n0+tx)];
  __syncthreads();
  #pragma unroll
  for (int r=0;r<32;r+=8)
    Wt[(size_t)(n0+ty+r)*K + (k0+tx)] = f2b(tl[tx][ty+r]);
}

// ---------------- layernorm: f32 in -> bf16 out
__global__ __launch_bounds__(256) void ln_fwd(const float* __restrict__ x,
                                              const float* __restrict__ g,
                                              const float* __restrict__ bta,
                                              u16* __restrict__ out){
  const int row = blockIdx.x, t = threadIdx.x;
  const float4 v = ((const float4*)(x + (size_t)row*DIM))[t];
  float s  = v.x+v.y+v.z+v.w;
  float s2 = v.x*v.x+v.y*v.y+v.z*v.z+v.w*v.w;
  #pragma unroll
  for (int m=1;m<64;m<<=1){ s += __shfl_xor(s,m); s2 += __shfl_xor(s2,m); }
  __shared__ float red[8];
  if ((t&63)==0){ red[t>>6]=s; red[4+(t>>6)]=s2; }
  __syncthreads();
  s  = red[0]+red[1]+red[2]+red[3];
  s2 = red[4]+red[5]+red[6]+red[7];
  const float mu = s*(1.0f/DIM);
  const float rstd = rsqrtf(s2*(1.0f/DIM) - mu*mu + 1e-5f);
  const float4 gv = ((const float4*)g)[t];
  const float4 bv = ((const float4*)bta)[t];
  ushort4 ov;
  ov.x = f2b((v.x-mu)*rstd*gv.x + bv.x);
  ov.y = f2b((v.y-mu)*rstd*gv.y + bv.y);
  ov.z = f2b((v.z-mu)*rstd*gv.z + bv.z);
  ov.w = f2b((v.w-mu)*rstd*gv.w + bv.w);
  ((ushort4*)out)[(size_t)row*(DIM/4) + t] = ov;
}

// ---------------- GEMM: C[M][N] = A[M][K](bf16) @ Bt[N][K](bf16)^T + bias, fused epilogues
template<int EPI>
__global__ __launch_bounds__(256) void gemm_bt(
    const u16* __restrict__ A, const u16* __restrict__ Bt,
    const float* __restrict__ bias, const float* __restrict__ resid,
    float* __restrict__ outf, u16* __restrict__ outh,
    u16* __restrict__ qo, u16* __restrict__ ko, u16* __restrict__ vo,
    int M, int N, int K)
{
  __shared__ __align__(16) u16 As[128*32];
  __shared__ __align__(16) u16 Bs[128*32];
  const int t = threadIdx.x, wv = t>>6, ln = t&63;
  const int nbx = gridDim.x, nwg = nbx*gridDim.y;
  const int bid = blockIdx.y*nbx + blockIdx.x;
  const int cpx = nwg>>3;
  const int wid = (bid&7)*cpx + (bid>>3);
  const int m0 = (wid/nbx)*128, n0 = (wid%nbx)*128;
  const int wr = wv>>1, wc = wv&1;
  const int lr = (ln>>4)*4, lc = ln&15, kb8 = (ln>>4)*8;
  f32x4 acc[4][4] = {};
  for (int kt=0; kt<K; kt+=32){
    #pragma unroll
    for (int j=0;j<2;j++){
      const int chunk = wv*2+j;
      const int byteoff = (chunk<<10) + (ln<<4);
      const int row = byteoff>>6;
      const int colb = byteoff&63;
      load_lds16((const char*)(A  + (size_t)(m0+row)*K + kt) + colb, (char*)As + (chunk<<10));
      load_lds16((const char*)(Bt + (size_t)(n0+row)*K + kt) + colb, (char*)Bs + (chunk<<10));
    }
    asm volatile("s_waitcnt vmcnt(0)" ::: "memory");
    __syncthreads();
    bf16x8 af[4], bfr[4];
    #pragma unroll
    for (int mi=0;mi<4;mi++)
      af[mi] = *(const bf16x8*)&As[(wr*64 + mi*16 + lc)*32 + kb8];
    #pragma unroll
    for (int ni=0;ni<4;ni++)
      bfr[ni] = *(const bf16x8*)&Bs[(wc*64 + ni*16 + lc)*32 + kb8];
    #pragma unroll
    for (int mi=0;mi<4;mi++)
      #pragma unroll
      for (int ni=0;ni<4;ni++)
        acc[mi][ni] = __builtin_amdgcn_mfma_f32_16x16x32_bf16(af[mi], bfr[ni], acc[mi][ni], 0,0,0);
    __syncthreads();
  }
  #pragma unroll
  for (int ni=0;ni<4;ni++){
    const int gn = n0 + wc*64 + ni*16 + lc;
    const float bv = bias[gn];
    #pragma unroll
    for (int mi=0;mi<4;mi++){
      const int gmb = m0 + wr*64 + mi*16 + lr;
      f32x4 a = acc[mi][ni];
      if constexpr (EPI==0){
        const int part = gn>>10, c = gn&1023;
        const int h = c>>6, d = c&63;
        const int bb = gmb>>11, tok0 = gmb&2047;
        if (part==2){
          ushort4 sv;
          sv.x = f2b(a[0]+bv); sv.y = f2b(a[1]+bv);
          sv.z = f2b(a[2]+bv); sv.w = f2b(a[3]+bv);
          *(ushort4*)&vo[(((size_t)bb*NHEADS + h)*HD + d)*TT + tok0] = sv;
        } else {
          u16* dst = part ? ko : qo;
          #pragma unroll
          for (int i=0;i<4;i++)
            dst[(((size_t)bb*NHEADS + h)*TT + tok0 + i)*HD + d] = f2b(a[i]+bv);
        }
      } else {
        #pragma unroll
        for (int i=0;i<4;i++){
          const int gm = gmb + i;
          float val = a[i] + bv;
          if constexpr (EPI==1){
            const size_t idx = (size_t)gm*DIM + gn;
            outf[idx] = val + resid[idx];
          } else if constexpr (EPI==2){
            const float gl = 0.5f*val*(1.0f + erff(val*0.70710678118654752f));
            outh[(size_t)gm*HID + gn] = f2b(gl);
          } else {
            const size_t idx = (size_t)gm*DIM + gn;
            outf[idx] = val + resid[idx];
          }
        }
      }
    }
  }
}

// ---------------- causal flash attention: QBLK=128, 8 waves x 16 rows,
// 2-phase prefetch, swizzled LDS. V pre-transposed: vtb is [B,H,hd,T].
// Grid: x=16 (qb), y=64 (bh), XCD-bijective remap.
__global__ __launch_bounds__(512) void attn_fwd(
    const u16* __restrict__ qpt, const u16* __restrict__ kb, const u16* __restrict__ vtb,
    u16* __restrict__ o)
{
  __shared__ __align__(16) u16 Kd[2][64*64];
  __shared__ __align__(16) u16 Vd[2][64*64];
  __shared__ __align__(16) u32 Ps[8][16*40];
  const int t = threadIdx.x, wv = t>>6, ln = t&63;
  const int bid  = blockIdx.y*gridDim.x + blockIdx.x;      // 0..1023
  const int orig = (bid&7)*128 + (bid>>3);
  const int bh   = orig>>4;
  const int qb   = 15 - (orig&15);                          // heavy-first
  const size_t base = (size_t)bh*TT*HD;
  const int hi = ln>>4, lc = ln&15;
  const int nt = 2*qb + 2;
  const int qbase = qb*128 + wv*16;        // wave's 16 q-rows
  const int qrow  = qbase + lc;            // lane's softmax row

  const bf16x8 qf0 = *(const bf16x8*)(qpt + base + (size_t)qrow*HD + hi*8);
  const bf16x8 qf1 = *(const bf16x8*)(qpt + base + (size_t)qrow*HD + 32 + hi*8);
  f32x4 oacc[4] = {};
  float mrun = -1e30f, lrun = 0.f;
  const float SCQ = 0.125f * 1.44269504f;  // 1/sqrt(64)*log2e
  u32* pw = Ps[wv];

  // staging: thread stages one 16B chunk of K and one of V (512 thr = 8KB each)
  const int srow = t>>3;                   // 0..63
  const int sch  = t&7;                    // LDS chunk (linear dest)
  const int gch  = (sch ^ (srow&7))<<3;    // pre-swizzled source column (elems)

  auto STAGE = [&](int nb, int kt){
    load_lds16(kb  + base + (size_t)(kt*64+srow)*HD + gch, &Kd[nb][srow*64 + sch*8]);
    load_lds16(vtb + base + (size_t)srow*TT + kt*64 + gch, &Vd[nb][srow*64 + sch*8]);
  };
  auto FRAG = [&](const u16* buf, int r, int ch)->bf16x8{
    return *(const bf16x8*)(buf + r*64 + ((ch ^ (r&7))<<3));
  };

  int cur = 0;
  STAGE(0, 0);
  asm volatile("s_waitcnt vmcnt(0)" ::: "memory");
  __syncthreads();

  for (int kt=0; kt<nt; kt++){
    if (kt+1 < nt) STAGE(cur^1, kt+1);
    const u16* Kb = Kd[cur];
    const u16* Vb = Vd[cur];
    if (kt*64 <= qbase + 15){              // not a fully-future tile
      float p[4][4];
      float mx = -1e30f;
      __builtin_amdgcn_s_setprio(1);
      #pragma unroll
      for (int cf=0;cf<4;cf++){
        const int r = cf*16 + lc;
        const bf16x8 kf0 = FRAG(Kb, r, hi);
        const bf16x8 kf1 = FRAG(Kb, r, hi+4);
        f32x4 z = {0.f,0.f,0.f,0.f};
        z = __builtin_amdgcn_mfma_f32_16x16x32_bf16(kf0, qf0, z, 0,0,0);
        z = __builtin_amdgcn_mfma_f32_16x16x32_bf16(kf1, qf1, z, 0,0,0);
        p[cf][0]=z[0]; p[cf][1]=z[1]; p[cf][2]=z[2]; p[cf][3]=z[3];
      }
      __builtin_amdgcn_s_setprio(0);
      if (kt*64 + 63 > qbase){             // diagonal tile: apply causal mask
        #pragma unroll
        for (int cf=0;cf<4;cf++)
          #pragma unroll
          for (int i=0;i<4;i++){
            const int kvg = kt*64 + cf*16 + 4*hi + i;
            float sv = p[cf][i]*SCQ;
            sv = (kvg > qrow) ? -1e30f : sv;
            p[cf][i] = sv;
            mx = fmaxf(mx, sv);
          }
      } else {
        #pragma unroll
        for (int cf=0;cf<4;cf++)
          #pragma unroll
          for (int i=0;i<4;i++){
            const float sv = p[cf][i]*SCQ;
            p[cf][i] = sv;
            mx = fmaxf(mx, sv);
          }
      }
      mx = fmaxf(mx, __shfl_xor(mx, 16));
      mx = fmaxf(mx, __shfl_xor(mx, 32));
      if (__any(mx > mrun + 11.0f)){
        const float mnew = fmaxf(mrun, mx);
        const float sc = exp2f(mrun - mnew);
        mrun = mnew;
        lrun *= sc;
        const float s0 = __shfl(sc, 4*hi+0);
        const float s1 = __shfl(sc, 4*hi+1);
        const float s2 = __shfl(sc, 4*hi+2);
        const float s3 = __shfl(sc, 4*hi+3);
        #pragma unroll
        for (int df=0;df<4;df++){
          oacc[df][0] *= s0; oacc[df][1] *= s1;
          oacc[df][2] *= s2; oacc[df][3] *= s3;
        }
      }
      float ssum = 0.f;
      #pragma unroll
      for (int cf=0;cf<4;cf++)
        #pragma unroll
        for (int i=0;i<4;i++){
          const float pv = exp2f(p[cf][i] - mrun);
          p[cf][i] = pv;
          ssum += pv;
        }
      ssum += __shfl_xor(ssum, 16);
      ssum += __shfl_xor(ssum, 32);
      lrun += ssum;
      #pragma unroll
      for (int cf=0;cf<4;cf++){
        uint2 wpk;
        wpk.x = (u32)f2b(p[cf][0]) | ((u32)f2b(p[cf][1])<<16);
        wpk.y = (u32)f2b(p[cf][2]) | ((u32)f2b(p[cf][3])<<16);
        *(uint2*)&pw[lc*40 + cf*8 + 2*hi] = wpk;
      }
      asm volatile("s_waitcnt lgkmcnt(0)" ::: "memory");
      __builtin_amdgcn_sched_barrier(0);
      const bf16x8 paA = *(const bf16x8*)&pw[lc*40 + 4*hi];
      const bf16x8 paB = *(const bf16x8*)&pw[lc*40 + 16 + 4*hi];
      __builtin_amdgcn_s_setprio(1);
      #pragma unroll
      for (int df=0;df<4;df++){
        const bf16x8 v0 = FRAG(Vb, df*16+lc, hi);
        const bf16x8 v1 = FRAG(Vb, df*16+lc, hi+4);
        oacc[df] = __builtin_amdgcn_mfma_f32_16x16x32_bf16(paA, v0, oacc[df], 0,0,0);
        oacc[df] = __builtin_amdgcn_mfma_f32_16x16x32_bf16(paB, v1, oacc[df], 0,0,0);
      }
      __builtin_amdgcn_s_setprio(0);
    }
    asm volatile("s_waitcnt vmcnt(0)" ::: "memory");
    __syncthreads();
    cur ^= 1;
  }

  const int b = bh>>4, h = bh&15;
  const float l0 = __shfl(lrun, 4*hi+0);
  const float l1 = __shfl(lrun, 4*hi+1);
  const float l2 = __shfl(lrun, 4*hi+2);
  const float l3 = __shfl(lrun, 4*hi+3);
  const float inv[4] = {1.0f/l0, 1.0f/l1, 1.0f/l2, 1.0f/l3};
  const int qg0 = qbase + 4*hi;
  #pragma unroll
  for (int i=0;i<4;i++){
    const size_t rowb = ((size_t)b*TT + (size_t)(qg0 + i))*DIM + h*HD;
    #pragma unroll
    for (int df=0;df<4;df++)
      o[rowb + df*16 + lc] = f2b(oacc[df][i]*inv[i]);
  }
}

extern "C" void kernel_launch(void* const* d_in, const int* in_sizes, int n_in,
                              void* d_out, int out_size, void* d_ws, size_t ws_size,
                              hipStream_t stream){
  (void)in_sizes; (void)n_in; (void)out_size; (void)ws_size;
  const float* x     = (const float*)d_in[0];
  const float* ln1g  = (const float*)d_in[1];
  const float* ln1b  = (const float*)d_in[2];
  const float* qkvw  = (const float*)d_in[3];
  const float* qkvb  = (const float*)d_in[4];
  const float* projw = (const float*)d_in[5];
  const float* projb = (const float*)d_in[6];
  const float* ln2g  = (const float*)d_in[7];
  const float* ln2b  = (const float*)d_in[8];
  const float* ff1w  = (const float*)d_in[9];
  const float* ff1b  = (const float*)d_in[10];
  const float* ff2w  = (const float*)d_in[11];
  const float* ff2b  = (const float*)d_in[12];
  float* out = (float*)d_out;

  char* ws = (char*)d_ws;
  size_t off = 0;
  auto alloc = [&](size_t n){ char* p = ws + off; off += (n + 255) & ~(size_t)255; return p; };
  u16* wqkvt  = (u16*)alloc((size_t)3072*1024*2);
  u16* wprojt = (u16*)alloc((size_t)1024*1024*2);
  u16* wff1t  = (u16*)alloc((size_t)4096*1024*2);
  u16* wff2t  = (u16*)alloc((size_t)1024*4096*2);
  u16* h1     = (u16*)alloc((size_t)MTOK*DIM*2);
  u16* qbuf   = (u16*)alloc((size_t)MTOK*DIM*2);
  u16* kbuf   = (u16*)alloc((size_t)MTOK*DIM*2);
  u16* vbuf   = (u16*)alloc((size_t)MTOK*DIM*2);   // [B,H,hd,T] transposed
  u16* aout   = (u16*)alloc((size_t)MTOK*DIM*2);
  float* x2   = (float*)alloc((size_t)MTOK*DIM*4);
  u16* h2     = (u16*)alloc((size_t)MTOK*DIM*2);
  u16* act    = (u16*)alloc((size_t)MTOK*HID*2);

  wconv_t<<<dim3(1024/32, 3072/32), 256, 0, stream>>>(qkvw, wqkvt, 1024, 3072);
  wconv_t<<<dim3(1024/32, 1024/32), 256, 0, stream>>>(projw, wprojt, 1024, 1024);
  wconv_t<<<dim3(1024/32, 4096/32), 256, 0, stream>>>(ff1w, wff1t, 1024, 4096);
  wconv_t<<<dim3(4096/32, 1024/32), 256, 0, stream>>>(ff2w, wff2t, 4096, 1024);

  ln_fwd<<<MTOK, 256, 0, stream>>>(x, ln1g, ln1b, h1);

  gemm_bt<0><<<dim3(3072/128, MTOK/128), 256, 0, stream>>>(
      h1, wqkvt, qkvb, nullptr, nullptr, nullptr, qbuf, kbuf, vbuf, MTOK, 3072, 1024);

  attn_fwd<<<dim3(TT/128, BB*NHEADS), 512, 0, stream>>>(qbuf, kbuf, vbuf, aout);

  gemm_bt<1><<<dim3(1024/128, MTOK/128), 256, 0, stream>>>(
      aout, wprojt, projb, x, x2, nullptr, nullptr, nullptr, nullptr, MTOK, 1024, 1024);

  ln_fwd<<<MTOK, 256, 0, stream>>>(x2, ln2g, ln2b, h2);

  gemm_bt<2><<<dim3(4096/128, MTOK/128), 256, 0, stream>>>(
      h2, wff1t, ff1b, nullptr, nullptr, act, nullptr, nullptr, nullptr, MTOK, HID, 1024);

  gemm_bt<3><<<dim3(1024/128, MTOK/128), 256, 0, stream>>>(
      act, wff2t, ff2b, x2, out, nullptr, nullptr, nullptr, nullptr, MTOK, DIM, HID);
}

// Round 6
// 480.968 us; speedup vs baseline: 1.4647x; 1.0817x over previous
//
#include <hip/hip_runtime.h>
#include <hip/hip_bf16.h>
#include <math.h>

#define DIM 1024
#define NHEADS 16
#define HD 64
#define TT 2048
#define BB 4
#define MTOK (BB*TT)
#define HID 4096

typedef __attribute__((ext_vector_type(8))) short bf16x8;
typedef __attribute__((ext_vector_type(4))) float f32x4;
typedef unsigned short u16;
typedef unsigned int u32;

__device__ inline u16 f2b(float f){
  __hip_bfloat16 h = __float2bfloat16(f);
  return __builtin_bit_cast(u16, h);
}

__device__ inline void load_lds16(const void* g, void* l){
  __builtin_amdgcn_global_load_lds(
      (const __attribute__((address_space(1))) void*)g,
      (__attribute__((address_space(3))) void*)l,
      16, 0, 0);
}

// ---------------- weight transpose + f32->bf16 convert: Wt[n][k] = W[k][n]
__global__ __launch_bounds__(256) void wconv_t(const float* __restrict__ W,
                                               u16* __restrict__ Wt, int K, int N){
  __shared__ float tl[32][33];
  const int k0 = blockIdx.x*32, n0 = blockIdx.y*32;
  const int tx = threadIdx.x & 31, ty = threadIdx.x >> 5; // 32 x 8
  #pragma unroll
  for (int r=0;r<32;r+=8)
    tl[ty+r][tx] = W[(size_t)(k0+ty+r)*N + (n0+tx)];
  __syncthreads();
  #pragma unroll
  for (int r=0;r<32;r+=8)
    Wt[(size_t)(n0+ty+r)*K + (k0+tx)] = f2b(tl[tx][ty+r]);
}

// ---------------- layernorm: f32 in -> bf16 out
__global__ __launch_bounds__(256) void ln_fwd(const float* __restrict__ x,
                                              const float* __restrict__ g,
                                              const float* __restrict__ bta,
                                              u16* __restrict__ out){
  const int row = blockIdx.x, t = threadIdx.x;
  const float4 v = ((const float4*)(x + (size_t)row*DIM))[t];
  float s  = v.x+v.y+v.z+v.w;
  float s2 = v.x*v.x+v.y*v.y+v.z*v.z+v.w*v.w;
  #pragma unroll
  for (int m=1;m<64;m<<=1){ s += __shfl_xor(s,m); s2 += __shfl_xor(s2,m); }
  __shared__ float red[8];
  if ((t&63)==0){ red[t>>6]=s; red[4+(t>>6)]=s2; }
  __syncthreads();
  s  = red[0]+red[1]+red[2]+red[3];
  s2 = red[4]+red[5]+red[6]+red[7];
  const float mu = s*(1.0f/DIM);
  const float rstd = rsqrtf(s2*(1.0f/DIM) - mu*mu + 1e-5f);
  const float4 gv = ((const float4*)g)[t];
  const float4 bv = ((const float4*)bta)[t];
  ushort4 ov;
  ov.x = f2b((v.x-mu)*rstd*gv.x + bv.x);
  ov.y = f2b((v.y-mu)*rstd*gv.y + bv.y);
  ov.z = f2b((v.z-mu)*rstd*gv.z + bv.z);
  ov.w = f2b((v.w-mu)*rstd*gv.w + bv.w);
  ((ushort4*)out)[(size_t)row*(DIM/4) + t] = ov;
}

// ---------------- GEMM: C[M][N] = A[M][K](bf16) @ Bt[N][K](bf16)^T + bias
// BK=64, XOR-swizzled LDS (both-sides), LDS-bounce epilogue for bf16 outputs.
// EPI 0: qkv split -> q [B,H,T,hd] / k [B,H,T,hd] / v^T [B,H,hd,T]  (bf16)
// EPI 1: + resid(f32) -> outf (x2)                 [direct f32 stores]
// EPI 2: exact gelu -> outh (act, row stride HID)  [bounce]
// EPI 3: + resid(f32) -> outf (final out)          [direct f32 stores]
template<int EPI>
__global__ __launch_bounds__(256) void gemm_bt(
    const u16* __restrict__ A, const u16* __restrict__ Bt,
    const float* __restrict__ bias, const float* __restrict__ resid,
    float* __restrict__ outf, u16* __restrict__ outh,
    u16* __restrict__ qo, u16* __restrict__ ko, u16* __restrict__ vo,
    int M, int N, int K)
{
  __shared__ __align__(16) u16 smem[16384];   // 32KB: As(16K) | Bs(16K), reused as Ct
  u16* As = smem;
  u16* Bs = smem + 8192;
  u16* Ct = smem;
  const int t = threadIdx.x, wv = t>>6, ln = t&63;
  const int nbx = gridDim.x, nwg = nbx*gridDim.y;
  const int bid = blockIdx.y*nbx + blockIdx.x;
  const int cpx = nwg>>3;
  const int wid = (bid&7)*cpx + (bid>>3);
  const int m0 = (wid/nbx)*128, n0 = (wid%nbx)*128;
  const int wr = wv>>1, wc = wv&1;
  const int hi = ln>>4, lr = hi*4, lc = ln&15;
  f32x4 acc[4][4] = {};

  // fragment read byte offsets (swizzled chunk): row&7 == lc&7 for all frags
  int rdoff[2][2]; // [kk][half: hi or hi+4]... chunk = kk*4 + hi
  #pragma unroll
  for (int kk=0; kk<2; kk++)
    rdoff[kk][0] = ((kk*4 + hi) ^ (lc&7)) << 3;   // in u16 units

  for (int kt=0; kt<K; kt+=64){
    #pragma unroll
    for (int j=0;j<4;j++){
      const int chunk = j*256 + t;          // 0..1023
      const int row = chunk>>3;
      const int cS  = (chunk&7) ^ (row&7);  // inverse-swizzled source column chunk
      load_lds16(A  + (size_t)(m0+row)*K + kt + cS*8, (char*)As + chunk*16);
      load_lds16(Bt + (size_t)(n0+row)*K + kt + cS*8, (char*)Bs + chunk*16);
    }
    asm volatile("s_waitcnt vmcnt(0)" ::: "memory");
    __syncthreads();
    bf16x8 af[4][2], bfr[4][2];
    #pragma unroll
    for (int mi=0;mi<4;mi++){
      const int rbase = (wr*64 + mi*16 + lc) << 6;
      af[mi][0] = *(const bf16x8*)&As[rbase + rdoff[0][0]];
      af[mi][1] = *(const bf16x8*)&As[rbase + rdoff[1][0]];
    }
    #pragma unroll
    for (int ni=0;ni<4;ni++){
      const int rbase = (wc*64 + ni*16 + lc) << 6;
      bfr[ni][0] = *(const bf16x8*)&Bs[rbase + rdoff[0][0]];
      bfr[ni][1] = *(const bf16x8*)&Bs[rbase + rdoff[1][0]];
    }
    #pragma unroll
    for (int kk=0;kk<2;kk++)
      #pragma unroll
      for (int mi=0;mi<4;mi++)
        #pragma unroll
        for (int ni=0;ni<4;ni++)
          acc[mi][ni] = __builtin_amdgcn_mfma_f32_16x16x32_bf16(af[mi][kk], bfr[ni][kk], acc[mi][ni], 0,0,0);
    __syncthreads();
  }

  if constexpr (EPI==1 || EPI==3){
    // direct f32 stores (full 64B lines per 16-lane group)
    #pragma unroll
    for (int ni=0;ni<4;ni++){
      const int gn = n0 + wc*64 + ni*16 + lc;
      const float bv = bias[gn];
      #pragma unroll
      for (int mi=0;mi<4;mi++){
        const int gmb = m0 + wr*64 + mi*16 + lr;
        f32x4 a = acc[mi][ni];
        #pragma unroll
        for (int i=0;i<4;i++){
          const size_t idx = (size_t)(gmb+i)*DIM + gn;
          outf[idx] = a[i] + bv + resid[idx];
        }
      }
    }
  } else {
    // bounce through swizzled Ct[128][128] u16 (EPI0: v-part transposed)
    const int part = (EPI==0) ? (n0>>10) : 0;
    #pragma unroll
    for (int ni=0;ni<4;ni++){
      const int gn = n0 + wc*64 + ni*16 + lc;
      const float bv = bias[gn];
      const int cl = wc*64 + ni*16 + lc;      // col within tile
      #pragma unroll
      for (int mi=0;mi<4;mi++){
        f32x4 a = acc[mi][ni];
        #pragma unroll
        for (int i=0;i<4;i++){
          const int rl = wr*64 + mi*16 + lr + i;  // row within tile
          float val = a[i] + bv;
          if constexpr (EPI==2)
            val = 0.5f*val*(1.0f + erff(val*0.70710678118654752f));
          int r, c;
          if (EPI==0 && part==2){ r = cl; c = rl; } else { r = rl; c = cl; }
          const int chunk = c>>3;
          const int csw = (chunk&8) | ((chunk ^ (r&7)) & 7);
          Ct[(r<<7) + (csw<<3) + (c&7)] = f2b(val);
        }
      }
    }
    __syncthreads();
    // vectorized readout: 8-lane groups copy contiguous 128B
    const int cid = t & 7, rsub = t >> 3;   // rsub 0..31
    const int bb = m0>>11, tok0b = m0&2047;
    const int h0 = (EPI==0) ? ((n0&1023)>>6) : 0;
    #pragma unroll
    for (int pass=0; pass<4; ++pass){
      const int rr = pass*32 + rsub;
      #pragma unroll
      for (int hh=0; hh<2; ++hh){
        const int chunk = hh*8 + cid;
        const int sw = (chunk&8) | ((chunk ^ (rr&7)) & 7);
        const bf16x8 vvv = *(const bf16x8*)&Ct[(rr<<7) + (sw<<3)];
        if constexpr (EPI==2){
          *(bf16x8*)&outh[(size_t)(m0+rr)*HID + n0 + chunk*8] = vvv;
        } else {
          if (part==2){
            const int head = h0 + (rr>>6), d = rr&63;
            *(bf16x8*)&vo[(((size_t)bb*NHEADS + head)*HD + d)*TT + tok0b + chunk*8] = vvv;
          } else {
            u16* dst = part ? ko : qo;
            const int head = h0 + hh;
            *(bf16x8*)&dst[(((size_t)bb*NHEADS + head)*TT + tok0b + rr)*HD + cid*8] = vvv;
          }
        }
      }
    }
  }
}

// ---------------- causal flash attention: QBLK=128, 8 waves x 16 rows,
// 2-phase prefetch, swizzled LDS. V pre-transposed: vtb is [B,H,hd,T].
// Grid: x=16 (qb), y=64 (bh), XCD-bijective remap.
__global__ __launch_bounds__(512) void attn_fwd(
    const u16* __restrict__ qpt, const u16* __restrict__ kb, const u16* __restrict__ vtb,
    u16* __restrict__ o)
{
  __shared__ __align__(16) u16 Kd[2][64*64];
  __shared__ __align__(16) u16 Vd[2][64*64];
  __shared__ __align__(16) u32 Ps[8][16*40];
  const int t = threadIdx.x, wv = t>>6, ln = t&63;
  const int bid  = blockIdx.y*gridDim.x + blockIdx.x;      // 0..1023
  const int orig = (bid&7)*128 + (bid>>3);
  const int bh   = orig>>4;
  const int qb   = 15 - (orig&15);                          // heavy-first
  const size_t base = (size_t)bh*TT*HD;
  const int hi = ln>>4, lc = ln&15;
  const int nt = 2*qb + 2;
  const int qbase = qb*128 + wv*16;        // wave's 16 q-rows
  const int qrow  = qbase + lc;            // lane's softmax row

  const bf16x8 qf0 = *(const bf16x8*)(qpt + base + (size_t)qrow*HD + hi*8);
  const bf16x8 qf1 = *(const bf16x8*)(qpt + base + (size_t)qrow*HD + 32 + hi*8);
  f32x4 oacc[4] = {};
  float mrun = -1e30f, lrun = 0.f;
  const float SCQ = 0.125f * 1.44269504f;  // 1/sqrt(64)*log2e
  u32* pw = Ps[wv];

  const int srow = t>>3;                   // 0..63
  const int sch  = t&7;                    // LDS chunk (linear dest)
  const int gch  = (sch ^ (srow&7))<<3;    // pre-swizzled source column (elems)

  auto STAGE = [&](int nb, int kt){
    load_lds16(kb  + base + (size_t)(kt*64+srow)*HD + gch, &Kd[nb][srow*64 + sch*8]);
    load_lds16(vtb + base + (size_t)srow*TT + kt*64 + gch, &Vd[nb][srow*64 + sch*8]);
  };
  auto FRAG = [&](const u16* buf, int r, int ch)->bf16x8{
    return *(const bf16x8*)(buf + r*64 + ((ch ^ (r&7))<<3));
  };

  int cur = 0;
  STAGE(0, 0);
  asm volatile("s_waitcnt vmcnt(0)" ::: "memory");
  __syncthreads();

  for (int kt=0; kt<nt; kt++){
    if (kt+1 < nt) STAGE(cur^1, kt+1);
    const u16* Kb = Kd[cur];
    const u16* Vb = Vd[cur];
    if (kt*64 <= qbase + 15){              // not a fully-future tile
      float p[4][4];
      float mx = -1e30f;
      __builtin_amdgcn_s_setprio(1);
      #pragma unroll
      for (int cf=0;cf<4;cf++){
        const int r = cf*16 + lc;
        const bf16x8 kf0 = FRAG(Kb, r, hi);
        const bf16x8 kf1 = FRAG(Kb, r, hi+4);
        f32x4 z = {0.f,0.f,0.f,0.f};
        z = __builtin_amdgcn_mfma_f32_16x16x32_bf16(kf0, qf0, z, 0,0,0);
        z = __builtin_amdgcn_mfma_f32_16x16x32_bf16(kf1, qf1, z, 0,0,0);
        p[cf][0]=z[0]; p[cf][1]=z[1]; p[cf][2]=z[2]; p[cf][3]=z[3];
      }
      __builtin_amdgcn_s_setprio(0);
      if (kt*64 + 63 > qbase){             // diagonal tile: apply causal mask
        #pragma unroll
        for (int cf=0;cf<4;cf++)
          #pragma unroll
          for (int i=0;i<4;i++){
            const int kvg = kt*64 + cf*16 + 4*hi + i;
            float sv = p[cf][i]*SCQ;
            sv = (kvg > qrow) ? -1e30f : sv;
            p[cf][i] = sv;
            mx = fmaxf(mx, sv);
          }
      } else {
        #pragma unroll
        for (int cf=0;cf<4;cf++)
          #pragma unroll
          for (int i=0;i<4;i++){
            const float sv = p[cf][i]*SCQ;
            p[cf][i] = sv;
            mx = fmaxf(mx, sv);
          }
      }
      mx = fmaxf(mx, __shfl_xor(mx, 16));
      mx = fmaxf(mx, __shfl_xor(mx, 32));
      if (__any(mx > mrun + 11.0f)){
        const float mnew = fmaxf(mrun, mx);
        const float sc = exp2f(mrun - mnew);
        mrun = mnew;
        lrun *= sc;
        const float s0 = __shfl(sc, 4*hi+0);
        const float s1 = __shfl(sc, 4*hi+1);
        const float s2 = __shfl(sc, 4*hi+2);
        const float s3 = __shfl(sc, 4*hi+3);
        #pragma unroll
        for (int df=0;df<4;df++){
          oacc[df][0] *= s0; oacc[df][1] *= s1;
          oacc[df][2] *= s2; oacc[df][3] *= s3;
        }
      }
      float ssum = 0.f;
      #pragma unroll
      for (int cf=0;cf<4;cf++)
        #pragma unroll
        for (int i=0;i<4;i++){
          const float pv = exp2f(p[cf][i] - mrun);
          p[cf][i] = pv;
          ssum += pv;
        }
      ssum += __shfl_xor(ssum, 16);
      ssum += __shfl_xor(ssum, 32);
      lrun += ssum;
      #pragma unroll
      for (int cf=0;cf<4;cf++){
        uint2 wpk;
        wpk.x = (u32)f2b(p[cf][0]) | ((u32)f2b(p[cf][1])<<16);
        wpk.y = (u32)f2b(p[cf][2]) | ((u32)f2b(p[cf][3])<<16);
        *(uint2*)&pw[lc*40 + cf*8 + 2*hi] = wpk;
      }
      asm volatile("s_waitcnt lgkmcnt(0)" ::: "memory");
      __builtin_amdgcn_sched_barrier(0);
      const bf16x8 paA = *(const bf16x8*)&pw[lc*40 + 4*hi];
      const bf16x8 paB = *(const bf16x8*)&pw[lc*40 + 16 + 4*hi];
      __builtin_amdgcn_s_setprio(1);
      #pragma unroll
      for (int df=0;df<4;df++){
        const bf16x8 v0 = FRAG(Vb, df*16+lc, hi);
        const bf16x8 v1 = FRAG(Vb, df*16+lc, hi+4);
        oacc[df] = __builtin_amdgcn_mfma_f32_16x16x32_bf16(paA, v0, oacc[df], 0,0,0);
        oacc[df] = __builtin_amdgcn_mfma_f32_16x16x32_bf16(paB, v1, oacc[df], 0,0,0);
      }
      __builtin_amdgcn_s_setprio(0);
    }
    asm volatile("s_waitcnt vmcnt(0)" ::: "memory");
    __syncthreads();
    cur ^= 1;
  }

  const int b = bh>>4, h = bh&15;
  const float l0 = __shfl(lrun, 4*hi+0);
  const float l1 = __shfl(lrun, 4*hi+1);
  const float l2 = __shfl(lrun, 4*hi+2);
  const float l3 = __shfl(lrun, 4*hi+3);
  const float inv[4] = {1.0f/l0, 1.0f/l1, 1.0f/l2, 1.0f/l3};
  const int qg0 = qbase + 4*hi;
  #pragma unroll
  for (int i=0;i<4;i++){
    const size_t rowb = ((size_t)b*TT + (size_t)(qg0 + i))*DIM + h*HD;
    #pragma unroll
    for (int df=0;df<4;df++)
      o[rowb + df*16 + lc] = f2b(oacc[df][i]*inv[i]);
  }
}

extern "C" void kernel_launch(void* const* d_in, const int* in_sizes, int n_in,
                              void* d_out, int out_size, void* d_ws, size_t ws_size,
                              hipStream_t stream){
  (void)in_sizes; (void)n_in; (void)out_size; (void)ws_size;
  const float* x     = (const float*)d_in[0];
  const float* ln1g  = (const float*)d_in[1];
  const float* ln1b  = (const float*)d_in[2];
  const float* qkvw  = (const float*)d_in[3];
  const float* qkvb  = (const float*)d_in[4];
  const float* projw = (const float*)d_in[5];
  const float* projb = (const float*)d_in[6];
  const float* ln2g  = (const float*)d_in[7];
  const float* ln2b  = (const float*)d_in[8];
  const float* ff1w  = (const float*)d_in[9];
  const float* ff1b  = (const float*)d_in[10];
  const float* ff2w  = (const float*)d_in[11];
  const float* ff2b  = (const float*)d_in[12];
  float* out = (float*)d_out;

  char* ws = (char*)d_ws;
  size_t off = 0;
  auto alloc = [&](size_t n){ char* p = ws + off; off += (n + 255) & ~(size_t)255; return p; };
  u16* wqkvt  = (u16*)alloc((size_t)3072*1024*2);
  u16* wprojt = (u16*)alloc((size_t)1024*1024*2);
  u16* wff1t  = (u16*)alloc((size_t)4096*1024*2);
  u16* wff2t  = (u16*)alloc((size_t)1024*4096*2);
  u16* h1     = (u16*)alloc((size_t)MTOK*DIM*2);
  u16* qbuf   = (u16*)alloc((size_t)MTOK*DIM*2);
  u16* kbuf   = (u16*)alloc((size_t)MTOK*DIM*2);
  u16* vbuf   = (u16*)alloc((size_t)MTOK*DIM*2);   // [B,H,hd,T] transposed
  u16* aout   = (u16*)alloc((size_t)MTOK*DIM*2);
  float* x2   = (float*)alloc((size_t)MTOK*DIM*4);
  u16* h2     = (u16*)alloc((size_t)MTOK*DIM*2);
  u16* act    = (u16*)alloc((size_t)MTOK*HID*2);

  wconv_t<<<dim3(1024/32, 3072/32), 256, 0, stream>>>(qkvw, wqkvt, 1024, 3072);
  wconv_t<<<dim3(1024/32, 1024/32), 256, 0, stream>>>(projw, wprojt, 1024, 1024);
  wconv_t<<<dim3(1024/32, 4096/32), 256, 0, stream>>>(ff1w, wff1t, 1024, 4096);
  wconv_t<<<dim3(4096/32, 1024/32), 256, 0, stream>>>(ff2w, wff2t, 4096, 1024);

  ln_fwd<<<MTOK, 256, 0, stream>>>(x, ln1g, ln1b, h1);

  gemm_bt<0><<<dim3(3072/128, MTOK/128), 256, 0, stream>>>(
      h1, wqkvt, qkvb, nullptr, nullptr, nullptr, qbuf, kbuf, vbuf, MTOK, 3072, 1024);

  attn_fwd<<<dim3(TT/128, BB*NHEADS), 512, 0, stream>>>(qbuf, kbuf, vbuf, aout);

  gemm_bt<1><<<dim3(1024/128, MTOK/128), 256, 0, stream>>>(
      aout, wprojt, projb, x, x2, nullptr, nullptr, nullptr, nullptr, MTOK, 1024, 1024);

  ln_fwd<<<MTOK, 256, 0, stream>>>(x2, ln2g, ln2b, h2);

  gemm_bt<2><<<dim3(4096/128, MTOK/128), 256, 0, stream>>>(
      h2, wff1t, ff1b, nullptr, nullptr, act, nullptr, nullptr, nullptr, MTOK, HID, 1024);

  gemm_bt<3><<<dim3(1024/128, MTOK/128), 256, 0, stream>>>(
      act, wff2t, ff2b, x2, out, nullptr, nullptr, nullptr, nullptr, MTOK, DIM, HID);
}